// Round 1
// baseline (861.609 us; speedup 1.0000x reference)
//
#include <hip/hip_runtime.h>
#include <stdint.h>

#define HID 128
#define NNODES 50000
#define NEDGES 800000
#define WPL 98304  // bf16 weight elems per layer in wt scratch

typedef __attribute__((ext_vector_type(8))) short short8;
typedef __attribute__((ext_vector_type(4))) float floatx4;

__device__ __forceinline__ float bf2f(unsigned short h) {
    union { unsigned int u; float f; } v; v.u = ((unsigned int)h) << 16; return v.f;
}
__device__ __forceinline__ unsigned short f2bf(float f) {
    union { float f; unsigned int u; } v; v.f = f;
    unsigned int u = v.u;
    return (unsigned short)((u + 0x7fffu + ((u >> 16) & 1u)) >> 16);
}

// ---- convert all layer weights to bf16, transposed to [n][k] for MFMA B-frags ----
__global__ __launch_bounds__(256) void cvt_weights(
    const float* __restrict__ mW1, const float* __restrict__ mW2,
    const float* __restrict__ uW1, const float* __restrict__ uW2,
    unsigned short* __restrict__ wt)
{
    int id = blockIdx.x * 256 + threadIdx.x;
    int l = id / WPL;
    int r = id - l * WPL;
    float v;
    if (r < 16384)      { int n = r >> 7, k = r & 127;                v = mW1[(l*257 + k)*128 + n]; }        // W1a^T
    else if (r < 32768) { int q = r - 16384; int n = q >> 7, k = q & 127; v = mW1[(l*257 + 128 + k)*128 + n]; } // W1b^T
    else if (r < 49152) { int q = r - 32768; int n = q >> 7, k = q & 127; v = mW2[(l*128 + k)*128 + n]; }      // W2^T
    else if (r < 81920) { int q = r - 49152; int n = q >> 8, k = q & 255; v = uW1[(l*256 + k)*128 + n]; }      // U1^T [128][256]
    else                { int q = r - 81920; int n = q >> 7, k = q & 127; v = uW2[(l*128 + k)*128 + n]; }      // U2^T
    wt[id] = f2bf(v);
}

// ---- encoder: x0 = node_feat @ enc_W + enc_b, write bf16 into u_in[:,0:128] ----
__global__ __launch_bounds__(256) void encoder_k(
    const float* __restrict__ nf, const float* __restrict__ W,
    const float* __restrict__ b, unsigned short* __restrict__ u_in)
{
    int id = blockIdx.x * 256 + threadIdx.x;   // exact: 50000*128 threads
    int n = id >> 7, c = id & 127;
    float acc = b[c];
    #pragma unroll
    for (int k = 0; k < 5; ++k) acc += nf[n*5 + k] * W[k*128 + c];
    u_in[n*256 + c] = f2bf(acc);
}

// ---- CSR build: histogram, single-block scan, placement ----
__global__ __launch_bounds__(256) void hist_k(const int* __restrict__ dst, int* __restrict__ cnt) {
    int e = blockIdx.x * 256 + threadIdx.x;
    atomicAdd(&cnt[dst[e]], 1);
}

__global__ __launch_bounds__(1024) void scan_k(const int* __restrict__ cnt, int* __restrict__ offs,
                                               int* __restrict__ cursor, int N) {
    __shared__ int buf[1024];
    int tid = threadIdx.x;
    int carry = 0;
    for (int base = 0; base < N; base += 1024) {
        int i = base + tid;
        int v = (i < N) ? cnt[i] : 0;
        buf[tid] = v;
        __syncthreads();
        for (int off = 1; off < 1024; off <<= 1) {
            int t = (tid >= off) ? buf[tid - off] : 0;
            __syncthreads();
            buf[tid] += t;
            __syncthreads();
        }
        int excl = buf[tid] - v + carry;
        if (i < N) { offs[i] = excl; cursor[i] = excl; }
        carry += buf[1023];
        __syncthreads();
    }
}

__global__ __launch_bounds__(256) void place_k(
    const int* __restrict__ src, const int* __restrict__ dst,
    const float* __restrict__ ea, int* __restrict__ cursor, int2* __restrict__ sorted)
{
    int e = blockIdx.x * 256 + threadIdx.x;
    int d = dst[e];
    int pos = atomicAdd(&cursor[d], 1);
    int2 pr; pr.x = src[e]; pr.y = __float_as_int(ea[e]);
    sorted[pos] = pr;
}

// ---- per-node aggregation: Hb[n] = inv_deg * sum_e relu(P[n] + Q[src] + ea*w1c), bf16 out ----
__global__ __launch_bounds__(256) void aggregate_k(
    const unsigned short* __restrict__ P, const unsigned short* __restrict__ Q,
    const int2* __restrict__ sorted, const int* __restrict__ offs, const int* __restrict__ cnt,
    const float* __restrict__ w1c, unsigned short* __restrict__ Hb)
{
    int wave = threadIdx.x >> 6, lane = threadIdx.x & 63;
    int n = blockIdx.x * 4 + wave;      // grid exactly covers 50000
    int i0 = lane * 2;
    float2 w = *(const float2*)(w1c + i0);
    ushort2 p2 = *(const ushort2*)(P + n*128 + i0);
    float p0 = bf2f(p2.x), p1 = bf2f(p2.y);
    int s = offs[n], c = cnt[n];
    float a0 = 0.f, a1 = 0.f;
    for (int j = 0; j < c; ++j) {
        int2 pr = sorted[s + j];
        float eav = __int_as_float(pr.y);
        ushort2 q2 = *(const ushort2*)(Q + (long)pr.x*128 + i0);
        float h0 = p0 + bf2f(q2.x) + eav * w.x;
        float h1 = p1 + bf2f(q2.y) + eav * w.y;
        a0 += fmaxf(h0, 0.f);
        a1 += fmaxf(h1, 0.f);
    }
    float inv = 1.0f / fmaxf((float)c, 1.0f);
    ushort2 o; o.x = f2bf(a0 * inv); o.y = f2bf(a1 * inv);
    *(ushort2*)(Hb + n*128 + i0) = o;
}

// ---- MFMA GEMM: C[M,128] = A[M,K](bf16) @ B[K,128] (+bias, relu, deg-mask) ----
template<bool OUT_BF16, bool RELU, bool MASK>
__global__ __launch_bounds__(256) void gemm_k(
    const unsigned short* __restrict__ A, int lda,
    const unsigned short* __restrict__ Bt,   // [128][K] bf16 (transposed)
    const float* __restrict__ bias,          // nullable
    const int* __restrict__ cnt,             // for MASK (deg>0)
    void* __restrict__ C, int ldc, int M, int K)
{
    __shared__ unsigned short As[64][72];    // +8 pad: 2-way-max bank aliasing (free)
    __shared__ unsigned short Bs[128][72];
    int tid = threadIdx.x;
    int wave = tid >> 6, lane = tid & 63;
    int row0 = blockIdx.x * 64;
    floatx4 zero = {0.f, 0.f, 0.f, 0.f};
    floatx4 acc[8];
    #pragma unroll
    for (int t = 0; t < 8; ++t) acc[t] = zero;

    for (int k0 = 0; k0 < K; k0 += 64) {
        #pragma unroll
        for (int it = 0; it < 4; ++it) {     // A tile 64x64 bf16 (rows padded to 50048: no guard)
            int idx = it*1024 + tid*4;
            int r = idx >> 6, c = idx & 63;
            ushort4 v = *(const ushort4*)(A + (long)(row0 + r)*lda + k0 + c);
            *(ushort4*)(&As[r][c]) = v;
        }
        #pragma unroll
        for (int it = 0; it < 8; ++it) {     // B tile 128x64
            int idx = it*1024 + tid*4;
            int r = idx >> 6, c = idx & 63;
            ushort4 v = *(const ushort4*)(Bt + (long)r*K + k0 + c);
            *(ushort4*)(&Bs[r][c]) = v;
        }
        __syncthreads();
        #pragma unroll
        for (int kk = 0; kk < 64; kk += 32) {
            short8 af = *(const short8*)(&As[wave*16 + (lane & 15)][kk + (lane >> 4)*8]);
            #pragma unroll
            for (int t = 0; t < 8; ++t) {
                short8 bf = *(const short8*)(&Bs[t*16 + (lane & 15)][kk + (lane >> 4)*8]);
                acc[t] = __builtin_amdgcn_mfma_f32_16x16x32_bf16(af, bf, acc[t], 0, 0, 0);
            }
        }
        __syncthreads();
    }
    // epilogue: C/D layout col=lane&15, row=(lane>>4)*4+reg  [m89/m91-verified]
    int col_lane = lane & 15;
    int rbase = row0 + wave*16 + (lane >> 4)*4;
    #pragma unroll
    for (int t = 0; t < 8; ++t) {
        int col = t*16 + col_lane;
        float bv = bias ? bias[col] : 0.f;
        #pragma unroll
        for (int r = 0; r < 4; ++r) {
            int grow = rbase + r;
            if (grow < M) {
                float v = acc[t][r];
                float bb = bv;
                if (MASK) bb = (cnt[grow] > 0) ? bv : 0.f;
                v += bb;
                if (RELU) v = fmaxf(v, 0.f);
                if (OUT_BF16) ((unsigned short*)C)[(long)grow*ldc + col] = f2bf(v);
                else          ((float*)C)[(long)grow*ldc + col] = v;
            }
        }
    }
}

// ---- LayerNorm + relu, fp32 in, bf16 out into u_in[:,0:128] ----
__global__ __launch_bounds__(256) void ln_relu_k(
    const float* __restrict__ u2, const float* __restrict__ g,
    const float* __restrict__ b, unsigned short* __restrict__ u_in)
{
    int wave = threadIdx.x >> 6, lane = threadIdx.x & 63;
    int n = blockIdx.x * 4 + wave;
    int i0 = lane * 2;
    float2 v = *(const float2*)(u2 + (long)n*128 + i0);
    float s = v.x + v.y, ss = v.x*v.x + v.y*v.y;
    #pragma unroll
    for (int o = 32; o > 0; o >>= 1) { s += __shfl_down(s, o); ss += __shfl_down(ss, o); }
    s = __shfl(s, 0); ss = __shfl(ss, 0);
    float mu = s * (1.f/128.f);
    float var = ss * (1.f/128.f) - mu*mu;
    float rs = rsqrtf(var + 1e-5f);
    float y0 = fmaxf((v.x - mu)*rs*g[i0]   + b[i0],   0.f);
    float y1 = fmaxf((v.y - mu)*rs*g[i0+1] + b[i0+1], 0.f);
    ushort2 o2; o2.x = f2bf(y0); o2.y = f2bf(y1);
    *(ushort2*)(u_in + (long)n*256 + i0) = o2;
}

// ---- column sum over nodes (for the mean) ----
__global__ __launch_bounds__(256) void colsum_k(const unsigned short* __restrict__ u_in,
                                                float* __restrict__ sum, int N)
{
    __shared__ float buf[256];
    int c = threadIdx.x & 127, half = threadIdx.x >> 7;
    float a = 0.f;
    for (int n = blockIdx.x*2 + half; n < N; n += gridDim.x*2)
        a += bf2f(u_in[(long)n*256 + c]);
    buf[threadIdx.x] = a;
    __syncthreads();
    if (threadIdx.x < 128) atomicAdd(&sum[c], buf[threadIdx.x] + buf[threadIdx.x + 128]);
}

// ---- final tiny MLP on the mean (fp32) ----
__global__ __launch_bounds__(128) void final_k(
    const float* __restrict__ sum, const float* __restrict__ W1, const float* __restrict__ b1,
    const float* __restrict__ W2, const float* __restrict__ b2, float* __restrict__ out)
{
    __shared__ float gbuf[128], hbuf[128];
    int t = threadIdx.x;
    gbuf[t] = sum[t] * (1.f / 50000.f);
    __syncthreads();
    float a = b1[t];
    for (int k = 0; k < 128; ++k) a += gbuf[k] * W1[k*128 + t];
    hbuf[t] = fmaxf(a, 0.f);
    __syncthreads();
    float o = b2[t];
    for (int k = 0; k < 128; ++k) o += hbuf[k] * W2[k*128 + t];
    out[t] = o;
}

extern "C" void kernel_launch(void* const* d_in, const int* in_sizes, int n_in,
                              void* d_out, int out_size, void* d_ws, size_t ws_size,
                              hipStream_t stream)
{
    const float* node_feat = (const float*)d_in[0];
    const float* edge_attr = (const float*)d_in[1];
    const float* enc_W  = (const float*)d_in[2];
    const float* enc_b  = (const float*)d_in[3];
    const float* mlp_W1 = (const float*)d_in[4];
    const float* mlp_b1 = (const float*)d_in[5];
    const float* mlp_W2 = (const float*)d_in[6];
    const float* mlp_b2 = (const float*)d_in[7];
    const float* upd_W1 = (const float*)d_in[8];
    const float* upd_b1 = (const float*)d_in[9];
    const float* upd_W2 = (const float*)d_in[10];
    const float* upd_b2 = (const float*)d_in[11];
    const float* ln_g   = (const float*)d_in[12];
    const float* ln_b   = (const float*)d_in[13];
    const float* out_W1 = (const float*)d_in[14];
    const float* out_b1 = (const float*)d_in[15];
    const float* out_W2 = (const float*)d_in[16];
    const float* out_b2 = (const float*)d_in[17];
    const int* edge_index = (const int*)d_in[18];
    const int* e_src = edge_index;
    const int* e_dst = edge_index + NEDGES;

    // workspace layout (padded node rows = 50048; all offsets 512B-aligned)
    char* ws = (char*)d_ws;
    unsigned short* u_in = (unsigned short*)(ws + 0);          // [50048][256] bf16: [x | aggr]
    unsigned short* P    = (unsigned short*)(ws + 25624576);   // [50048][128] bf16 (reused as u_hid)
    unsigned short* Q    = (unsigned short*)(ws + 38436864);   // [50048][128] bf16
    unsigned short* Hb   = (unsigned short*)(ws + 51249152);   // [50048][128] bf16
    float* u2            = (float*)(ws + 64061440);            // [50048][128] fp32
    int2* sorted         = (int2*)(ws + 89686016);             // [800000] {src, ea}
    int* cnt             = (int*)(ws + 96086016);              // [50048]
    int* offs            = (int*)(ws + 96286208);              // [50048]
    int* cursor          = (int*)(ws + 96486400);              // [50048]
    unsigned short* wt   = (unsigned short*)(ws + 96686592);   // [3*WPL] bf16 weights
    float* sumv          = (float*)(ws + 97276416);            // [128]

    hipMemsetAsync(cnt, 0, 50048*4, stream);
    hipMemsetAsync(sumv, 0, 512, stream);
    cvt_weights<<<1152, 256, 0, stream>>>(mlp_W1, mlp_W2, upd_W1, upd_W2, wt);
    encoder_k<<<25000, 256, 0, stream>>>(node_feat, enc_W, enc_b, u_in);
    hist_k<<<3125, 256, 0, stream>>>(e_dst, cnt);
    scan_k<<<1, 1024, 0, stream>>>(cnt, offs, cursor, NNODES);
    place_k<<<3125, 256, 0, stream>>>(e_src, e_dst, edge_attr, cursor, sorted);

    for (int l = 0; l < 3; ++l) {
        const unsigned short* w1a = wt + l*WPL;
        const unsigned short* w1b = wt + l*WPL + 16384;
        const unsigned short* w2t = wt + l*WPL + 32768;
        const unsigned short* u1t = wt + l*WPL + 49152;
        const unsigned short* u2t = wt + l*WPL + 81920;
        // P = x@W1a + b1 ; Q = x@W1b   (b1 folded into P)
        gemm_k<true,false,false><<<782, 256, 0, stream>>>(u_in, 256, w1a, mlp_b1 + l*128, nullptr, P, 128, NNODES, 128);
        gemm_k<true,false,false><<<782, 256, 0, stream>>>(u_in, 256, w1b, nullptr,        nullptr, Q, 128, NNODES, 128);
        // Hb = inv_deg * segsum(relu(P[dst]+Q[src]+ea*w1c))
        aggregate_k<<<12500, 256, 0, stream>>>(P, Q, sorted, offs, cnt, mlp_W1 + (l*257 + 256)*128, Hb);
        // aggr = Hb@W2 + b2*[deg>0]  -> u_in[:,128:256]
        gemm_k<true,false,true><<<782, 256, 0, stream>>>(Hb, 128, w2t, mlp_b2 + l*128, cnt, u_in + 128, 256, NNODES, 128);
        // u_hid = relu([x|aggr]@U1 + ub1)   (K=256)
        gemm_k<true,true,false><<<782, 256, 0, stream>>>(u_in, 256, u1t, upd_b1 + l*128, nullptr, P, 128, NNODES, 256);
        // u2 = u_hid@U2 + ub2  (fp32 out)
        gemm_k<false,false,false><<<782, 256, 0, stream>>>(P, 128, u2t, upd_b2 + l*128, nullptr, u2, 128, NNODES, 128);
        // x = relu(LN(u2)*g+b) -> u_in[:,0:128] bf16
        ln_relu_k<<<12500, 256, 0, stream>>>(u2, ln_g + l*128, ln_b + l*128, u_in);
    }
    colsum_k<<<256, 256, 0, stream>>>(u_in, sumv, NNODES);
    final_k<<<1, 128, 0, stream>>>(sumv, out_W1, out_b1, out_W2, out_b2, (float*)d_out);
}

// Round 2
// 853.848 us; speedup vs baseline: 1.0091x; 1.0091x over previous
//
#include <hip/hip_runtime.h>
#include <stdint.h>

#define HID 128
#define NNODES 50000
#define NEDGES 800000
#define WPL 98304  // bf16 weight elems per layer in wt scratch

typedef __attribute__((ext_vector_type(8))) short short8;
typedef __attribute__((ext_vector_type(4))) float floatx4;

__device__ __forceinline__ float bf2f(unsigned short h) {
    union { unsigned int u; float f; } v; v.u = ((unsigned int)h) << 16; return v.f;
}
__device__ __forceinline__ unsigned short f2bf(float f) {
    union { float f; unsigned int u; } v; v.f = f;
    unsigned int u = v.u;
    return (unsigned short)((u + 0x7fffu + ((u >> 16) & 1u)) >> 16);
}

// ---- convert all layer weights to bf16, transposed to [n][k] for MFMA B-frags ----
__global__ __launch_bounds__(256) void cvt_weights(
    const float* __restrict__ mW1, const float* __restrict__ mW2,
    const float* __restrict__ uW1, const float* __restrict__ uW2,
    unsigned short* __restrict__ wt)
{
    int id = blockIdx.x * 256 + threadIdx.x;
    int l = id / WPL;
    int r = id - l * WPL;
    float v;
    if (r < 16384)      { int n = r >> 7, k = r & 127;                v = mW1[(l*257 + k)*128 + n]; }        // W1a^T
    else if (r < 32768) { int q = r - 16384; int n = q >> 7, k = q & 127; v = mW1[(l*257 + 128 + k)*128 + n]; } // W1b^T
    else if (r < 49152) { int q = r - 32768; int n = q >> 7, k = q & 127; v = mW2[(l*128 + k)*128 + n]; }      // W2^T
    else if (r < 81920) { int q = r - 49152; int n = q >> 8, k = q & 255; v = uW1[(l*256 + k)*128 + n]; }      // U1^T [128][256]
    else                { int q = r - 81920; int n = q >> 7, k = q & 127; v = uW2[(l*128 + k)*128 + n]; }      // U2^T
    wt[id] = f2bf(v);
}

// ---- encoder: x0 = node_feat @ enc_W + enc_b, write bf16 into u_in[:,0:128] ----
__global__ __launch_bounds__(256) void encoder_k(
    const float* __restrict__ nf, const float* __restrict__ W,
    const float* __restrict__ b, unsigned short* __restrict__ u_in)
{
    int id = blockIdx.x * 256 + threadIdx.x;   // exact: 50000*128 threads
    int n = id >> 7, c = id & 127;
    float acc = b[c];
    #pragma unroll
    for (int k = 0; k < 5; ++k) acc += nf[n*5 + k] * W[k*128 + c];
    u_in[n*256 + c] = f2bf(acc);
}

// ---- CSR build: histogram, single-block scan, placement ----
__global__ __launch_bounds__(256) void hist_k(const int* __restrict__ dst, int* __restrict__ cnt) {
    int e = blockIdx.x * 256 + threadIdx.x;
    atomicAdd(&cnt[dst[e]], 1);
}

// single-block scan, 2 barriers total: per-thread serial scan (49 items in regs)
// -> wave shfl-scan of thread totals -> 16-wave LDS scan -> writeback.
#define SCAN_ITEMS 49
__global__ __launch_bounds__(1024) void scan_k(const int* __restrict__ cnt, int* __restrict__ offs,
                                               int* __restrict__ cursor, int N) {
    __shared__ int wsum[16];
    int tid = threadIdx.x;
    int lane = tid & 63, wave = tid >> 6;
    int base = tid * SCAN_ITEMS;
    int v[SCAN_ITEMS];
    int tot = 0;
    #pragma unroll
    for (int i = 0; i < SCAN_ITEMS; ++i) {
        int idx = base + i;
        v[i] = (idx < N) ? cnt[idx] : 0;
        tot += v[i];
    }
    // inclusive wave scan of per-thread totals
    int sc = tot;
    #pragma unroll
    for (int o = 1; o < 64; o <<= 1) {
        int t = __shfl_up(sc, o);
        if (lane >= o) sc += t;
    }
    if (lane == 63) wsum[wave] = sc;
    __syncthreads();
    if (wave == 0 && lane < 16) {
        int w = wsum[lane];
        #pragma unroll
        for (int o = 1; o < 16; o <<= 1) {
            int t = __shfl_up(w, o);
            if (lane >= o) w += t;
        }
        wsum[lane] = w;
    }
    __syncthreads();
    int excl = sc - tot + (wave > 0 ? wsum[wave - 1] : 0);
    #pragma unroll
    for (int i = 0; i < SCAN_ITEMS; ++i) {
        int idx = base + i;
        if (idx < N) { offs[idx] = excl; cursor[idx] = excl; }
        excl += v[i];
    }
}

__global__ __launch_bounds__(256) void place_k(
    const int* __restrict__ src, const int* __restrict__ dst,
    const float* __restrict__ ea, int* __restrict__ cursor, int2* __restrict__ sorted)
{
    int e = blockIdx.x * 256 + threadIdx.x;
    int d = dst[e];
    int pos = atomicAdd(&cursor[d], 1);
    int2 pr; pr.x = src[e]; pr.y = __float_as_int(ea[e]);
    sorted[pos] = pr;
}

// ---- per-node aggregation: Hb[n] = inv_deg * sum_e relu(P[n] + Q[src] + ea*w1c), bf16 out ----
__global__ __launch_bounds__(256) void aggregate_k(
    const unsigned short* __restrict__ P, const unsigned short* __restrict__ Q,
    const int2* __restrict__ sorted, const int* __restrict__ offs, const int* __restrict__ cnt,
    const float* __restrict__ w1c, unsigned short* __restrict__ Hb)
{
    int wave = threadIdx.x >> 6, lane = threadIdx.x & 63;
    int n = blockIdx.x * 4 + wave;      // grid exactly covers 50000
    int i0 = lane * 2;
    float2 w = *(const float2*)(w1c + i0);
    ushort2 p2 = *(const ushort2*)(P + n*128 + i0);
    float p0 = bf2f(p2.x), p1 = bf2f(p2.y);
    int s = offs[n], c = cnt[n];
    float a0 = 0.f, a1 = 0.f;
    for (int j = 0; j < c; ++j) {
        int2 pr = sorted[s + j];
        float eav = __int_as_float(pr.y);
        ushort2 q2 = *(const ushort2*)(Q + (long)pr.x*128 + i0);
        float h0 = p0 + bf2f(q2.x) + eav * w.x;
        float h1 = p1 + bf2f(q2.y) + eav * w.y;
        a0 += fmaxf(h0, 0.f);
        a1 += fmaxf(h1, 0.f);
    }
    float inv = 1.0f / fmaxf((float)c, 1.0f);
    ushort2 o; o.x = f2bf(a0 * inv); o.y = f2bf(a1 * inv);
    *(ushort2*)(Hb + n*128 + i0) = o;
}

// ---- MFMA GEMM: C[M,128] = A[M,K](bf16) @ B[K,128] (+bias, relu, deg-mask) ----
template<bool OUT_BF16, bool RELU, bool MASK>
__global__ __launch_bounds__(256) void gemm_k(
    const unsigned short* __restrict__ A, int lda,
    const unsigned short* __restrict__ Bt,   // [128][K] bf16 (transposed)
    const float* __restrict__ bias,          // nullable
    const int* __restrict__ cnt,             // for MASK (deg>0)
    void* __restrict__ C, int ldc, int M, int K)
{
    __shared__ unsigned short As[64][72];    // +8 pad: 2-way-max bank aliasing (free)
    __shared__ unsigned short Bs[128][72];
    int tid = threadIdx.x;
    int wave = tid >> 6, lane = tid & 63;
    int row0 = blockIdx.x * 64;
    floatx4 zero = {0.f, 0.f, 0.f, 0.f};
    floatx4 acc[8];
    #pragma unroll
    for (int t = 0; t < 8; ++t) acc[t] = zero;

    for (int k0 = 0; k0 < K; k0 += 64) {
        #pragma unroll
        for (int it = 0; it < 4; ++it) {     // A tile 64x64 bf16 (rows padded to 50048: no guard)
            int idx = it*1024 + tid*4;
            int r = idx >> 6, c = idx & 63;
            ushort4 v = *(const ushort4*)(A + (long)(row0 + r)*lda + k0 + c);
            *(ushort4*)(&As[r][c]) = v;
        }
        #pragma unroll
        for (int it = 0; it < 8; ++it) {     // B tile 128x64
            int idx = it*1024 + tid*4;
            int r = idx >> 6, c = idx & 63;
            ushort4 v = *(const ushort4*)(Bt + (long)r*K + k0 + c);
            *(ushort4*)(&Bs[r][c]) = v;
        }
        __syncthreads();
        #pragma unroll
        for (int kk = 0; kk < 64; kk += 32) {
            short8 af = *(const short8*)(&As[wave*16 + (lane & 15)][kk + (lane >> 4)*8]);
            #pragma unroll
            for (int t = 0; t < 8; ++t) {
                short8 bf = *(const short8*)(&Bs[t*16 + (lane & 15)][kk + (lane >> 4)*8]);
                acc[t] = __builtin_amdgcn_mfma_f32_16x16x32_bf16(af, bf, acc[t], 0, 0, 0);
            }
        }
        __syncthreads();
    }
    // epilogue: C/D layout col=lane&15, row=(lane>>4)*4+reg  [m89/m91-verified]
    int col_lane = lane & 15;
    int rbase = row0 + wave*16 + (lane >> 4)*4;
    #pragma unroll
    for (int t = 0; t < 8; ++t) {
        int col = t*16 + col_lane;
        float bv = bias ? bias[col] : 0.f;
        #pragma unroll
        for (int r = 0; r < 4; ++r) {
            int grow = rbase + r;
            if (grow < M) {
                float v = acc[t][r];
                float bb = bv;
                if (MASK) bb = (cnt[grow] > 0) ? bv : 0.f;
                v += bb;
                if (RELU) v = fmaxf(v, 0.f);
                if (OUT_BF16) ((unsigned short*)C)[(long)grow*ldc + col] = f2bf(v);
                else          ((float*)C)[(long)grow*ldc + col] = v;
            }
        }
    }
}

// ---- LayerNorm + relu, fp32 in, bf16 out into u_in[:,0:128] ----
__global__ __launch_bounds__(256) void ln_relu_k(
    const float* __restrict__ u2, const float* __restrict__ g,
    const float* __restrict__ b, unsigned short* __restrict__ u_in)
{
    int wave = threadIdx.x >> 6, lane = threadIdx.x & 63;
    int n = blockIdx.x * 4 + wave;
    int i0 = lane * 2;
    float2 v = *(const float2*)(u2 + (long)n*128 + i0);
    float s = v.x + v.y, ss = v.x*v.x + v.y*v.y;
    #pragma unroll
    for (int o = 32; o > 0; o >>= 1) { s += __shfl_down(s, o); ss += __shfl_down(ss, o); }
    s = __shfl(s, 0); ss = __shfl(ss, 0);
    float mu = s * (1.f/128.f);
    float var = ss * (1.f/128.f) - mu*mu;
    float rs = rsqrtf(var + 1e-5f);
    float y0 = fmaxf((v.x - mu)*rs*g[i0]   + b[i0],   0.f);
    float y1 = fmaxf((v.y - mu)*rs*g[i0+1] + b[i0+1], 0.f);
    ushort2 o2; o2.x = f2bf(y0); o2.y = f2bf(y1);
    *(ushort2*)(u_in + (long)n*256 + i0) = o2;
}

// ---- column sum over nodes (for the mean) ----
__global__ __launch_bounds__(256) void colsum_k(const unsigned short* __restrict__ u_in,
                                                float* __restrict__ sum, int N)
{
    __shared__ float buf[256];
    int c = threadIdx.x & 127, half = threadIdx.x >> 7;
    float a = 0.f;
    for (int n = blockIdx.x*2 + half; n < N; n += gridDim.x*2)
        a += bf2f(u_in[(long)n*256 + c]);
    buf[threadIdx.x] = a;
    __syncthreads();
    if (threadIdx.x < 128) atomicAdd(&sum[c], buf[threadIdx.x] + buf[threadIdx.x + 128]);
}

// ---- final tiny MLP on the mean (fp32) ----
__global__ __launch_bounds__(128) void final_k(
    const float* __restrict__ sum, const float* __restrict__ W1, const float* __restrict__ b1,
    const float* __restrict__ W2, const float* __restrict__ b2, float* __restrict__ out)
{
    __shared__ float gbuf[128], hbuf[128];
    int t = threadIdx.x;
    gbuf[t] = sum[t] * (1.f / 50000.f);
    __syncthreads();
    float a = b1[t];
    for (int k = 0; k < 128; ++k) a += gbuf[k] * W1[k*128 + t];
    hbuf[t] = fmaxf(a, 0.f);
    __syncthreads();
    float o = b2[t];
    for (int k = 0; k < 128; ++k) o += hbuf[k] * W2[k*128 + t];
    out[t] = o;
}

extern "C" void kernel_launch(void* const* d_in, const int* in_sizes, int n_in,
                              void* d_out, int out_size, void* d_ws, size_t ws_size,
                              hipStream_t stream)
{
    const float* node_feat = (const float*)d_in[0];
    const float* edge_attr = (const float*)d_in[1];
    const float* enc_W  = (const float*)d_in[2];
    const float* enc_b  = (const float*)d_in[3];
    const float* mlp_W1 = (const float*)d_in[4];
    const float* mlp_b1 = (const float*)d_in[5];
    const float* mlp_W2 = (const float*)d_in[6];
    const float* mlp_b2 = (const float*)d_in[7];
    const float* upd_W1 = (const float*)d_in[8];
    const float* upd_b1 = (const float*)d_in[9];
    const float* upd_W2 = (const float*)d_in[10];
    const float* upd_b2 = (const float*)d_in[11];
    const float* ln_g   = (const float*)d_in[12];
    const float* ln_b   = (const float*)d_in[13];
    const float* out_W1 = (const float*)d_in[14];
    const float* out_b1 = (const float*)d_in[15];
    const float* out_W2 = (const float*)d_in[16];
    const float* out_b2 = (const float*)d_in[17];
    const int* edge_index = (const int*)d_in[18];
    const int* e_src = edge_index;
    const int* e_dst = edge_index + NEDGES;

    // workspace layout (padded node rows = 50048; all offsets 512B-aligned)
    char* ws = (char*)d_ws;
    unsigned short* u_in = (unsigned short*)(ws + 0);          // [50048][256] bf16: [x | aggr]
    unsigned short* P    = (unsigned short*)(ws + 25624576);   // [50048][128] bf16 (reused as u_hid)
    unsigned short* Q    = (unsigned short*)(ws + 38436864);   // [50048][128] bf16
    unsigned short* Hb   = (unsigned short*)(ws + 51249152);   // [50048][128] bf16
    float* u2            = (float*)(ws + 64061440);            // [50048][128] fp32
    int2* sorted         = (int2*)(ws + 89686016);             // [800000] {src, ea}
    int* cnt             = (int*)(ws + 96086016);              // [50048]
    int* offs            = (int*)(ws + 96286208);              // [50048]
    int* cursor          = (int*)(ws + 96486400);              // [50048]
    unsigned short* wt   = (unsigned short*)(ws + 96686592);   // [3*WPL] bf16 weights
    float* sumv          = (float*)(ws + 97276416);            // [128]

    hipMemsetAsync(cnt, 0, 50048*4, stream);
    hipMemsetAsync(sumv, 0, 512, stream);
    cvt_weights<<<1152, 256, 0, stream>>>(mlp_W1, mlp_W2, upd_W1, upd_W2, wt);
    encoder_k<<<25000, 256, 0, stream>>>(node_feat, enc_W, enc_b, u_in);
    hist_k<<<3125, 256, 0, stream>>>(e_dst, cnt);
    scan_k<<<1, 1024, 0, stream>>>(cnt, offs, cursor, NNODES);
    place_k<<<3125, 256, 0, stream>>>(e_src, e_dst, edge_attr, cursor, sorted);

    for (int l = 0; l < 3; ++l) {
        const unsigned short* w1a = wt + l*WPL;
        const unsigned short* w1b = wt + l*WPL + 16384;
        const unsigned short* w2t = wt + l*WPL + 32768;
        const unsigned short* u1t = wt + l*WPL + 49152;
        const unsigned short* u2t = wt + l*WPL + 81920;
        // P = x@W1a + b1 ; Q = x@W1b   (b1 folded into P)
        gemm_k<true,false,false><<<782, 256, 0, stream>>>(u_in, 256, w1a, mlp_b1 + l*128, nullptr, P, 128, NNODES, 128);
        gemm_k<true,false,false><<<782, 256, 0, stream>>>(u_in, 256, w1b, nullptr,        nullptr, Q, 128, NNODES, 128);
        // Hb = inv_deg * segsum(relu(P[dst]+Q[src]+ea*w1c))
        aggregate_k<<<12500, 256, 0, stream>>>(P, Q, sorted, offs, cnt, mlp_W1 + (l*257 + 256)*128, Hb);
        // aggr = Hb@W2 + b2*[deg>0]  -> u_in[:,128:256]
        gemm_k<true,false,true><<<782, 256, 0, stream>>>(Hb, 128, w2t, mlp_b2 + l*128, cnt, u_in + 128, 256, NNODES, 128);
        // u_hid = relu([x|aggr]@U1 + ub1)   (K=256)
        gemm_k<true,true,false><<<782, 256, 0, stream>>>(u_in, 256, u1t, upd_b1 + l*128, nullptr, P, 128, NNODES, 256);
        // u2 = u_hid@U2 + ub2  (fp32 out)
        gemm_k<false,false,false><<<782, 256, 0, stream>>>(P, 128, u2t, upd_b2 + l*128, nullptr, u2, 128, NNODES, 128);
        // x = relu(LN(u2)*g+b) -> u_in[:,0:128] bf16
        ln_relu_k<<<12500, 256, 0, stream>>>(u2, ln_g + l*128, ln_b + l*128, u_in);
    }
    colsum_k<<<256, 256, 0, stream>>>(u_in, sumv, NNODES);
    final_k<<<1, 128, 0, stream>>>(sumv, out_W1, out_b1, out_W2, out_b2, (float*)d_out);
}

// Round 3
// 734.533 us; speedup vs baseline: 1.1730x; 1.1624x over previous
//
#include <hip/hip_runtime.h>
#include <stdint.h>

#define HID 128
#define NNODES 50000
#define NEDGES 800000
#define WPL 98304  // bf16 weight elems per layer in wt scratch

typedef __attribute__((ext_vector_type(8))) short short8;
typedef __attribute__((ext_vector_type(4))) float floatx4;

__device__ __forceinline__ float bf2f(unsigned short h) {
    union { unsigned int u; float f; } v; v.u = ((unsigned int)h) << 16; return v.f;
}
__device__ __forceinline__ unsigned short f2bf(float f) {
    union { float f; unsigned int u; } v; v.f = f;
    unsigned int u = v.u;
    return (unsigned short)((u + 0x7fffu + ((u >> 16) & 1u)) >> 16);
}

// ---- convert all layer weights to bf16, transposed to [n][k] for MFMA B-frags ----
// layout per layer l: [W1a^T 128x128 | W1b^T 128x128 | W2^T 128x128 | U1^T 128x256 | U2^T 128x128]
// (W1a^T followed by W1b^T = 256 contiguous n-rows of K=128 -> the fused PQ B-matrix)
__global__ __launch_bounds__(256) void cvt_weights(
    const float* __restrict__ mW1, const float* __restrict__ mW2,
    const float* __restrict__ uW1, const float* __restrict__ uW2,
    unsigned short* __restrict__ wt)
{
    int id = blockIdx.x * 256 + threadIdx.x;
    int l = id / WPL;
    int r = id - l * WPL;
    float v;
    if (r < 16384)      { int n = r >> 7, k = r & 127;                v = mW1[(l*257 + k)*128 + n]; }
    else if (r < 32768) { int q = r - 16384; int n = q >> 7, k = q & 127; v = mW1[(l*257 + 128 + k)*128 + n]; }
    else if (r < 49152) { int q = r - 32768; int n = q >> 7, k = q & 127; v = mW2[(l*128 + k)*128 + n]; }
    else if (r < 81920) { int q = r - 49152; int n = q >> 8, k = q & 255; v = uW1[(l*256 + k)*128 + n]; }
    else                { int q = r - 81920; int n = q >> 7, k = q & 127; v = uW2[(l*128 + k)*128 + n]; }
    wt[id] = f2bf(v);
}

// ---- encoder: x0 = node_feat @ enc_W + enc_b, write bf16 into u_in[:,0:128] ----
__global__ __launch_bounds__(256) void encoder_k(
    const float* __restrict__ nf, const float* __restrict__ W,
    const float* __restrict__ b, unsigned short* __restrict__ u_in)
{
    int id = blockIdx.x * 256 + threadIdx.x;   // exact: 50000*128 threads
    int n = id >> 7, c = id & 127;
    float acc = b[c];
    #pragma unroll
    for (int k = 0; k < 5; ++k) acc += nf[n*5 + k] * W[k*128 + c];
    u_in[n*256 + c] = f2bf(acc);
}

// ---- CSR build: histogram, single-block scan, placement ----
__global__ __launch_bounds__(256) void hist_k(const int* __restrict__ dst, int* __restrict__ cnt) {
    int e = blockIdx.x * 256 + threadIdx.x;
    atomicAdd(&cnt[dst[e]], 1);
}

#define SCAN_ITEMS 49
__global__ __launch_bounds__(1024) void scan_k(const int* __restrict__ cnt, int* __restrict__ offs,
                                               int* __restrict__ cursor, int N) {
    __shared__ int wsum[16];
    int tid = threadIdx.x;
    int lane = tid & 63, wave = tid >> 6;
    int base = tid * SCAN_ITEMS;
    int v[SCAN_ITEMS];
    int tot = 0;
    #pragma unroll
    for (int i = 0; i < SCAN_ITEMS; ++i) {
        int idx = base + i;
        v[i] = (idx < N) ? cnt[idx] : 0;
        tot += v[i];
    }
    int sc = tot;
    #pragma unroll
    for (int o = 1; o < 64; o <<= 1) {
        int t = __shfl_up(sc, o);
        if (lane >= o) sc += t;
    }
    if (lane == 63) wsum[wave] = sc;
    __syncthreads();
    if (wave == 0 && lane < 16) {
        int w = wsum[lane];
        #pragma unroll
        for (int o = 1; o < 16; o <<= 1) {
            int t = __shfl_up(w, o);
            if (lane >= o) w += t;
        }
        wsum[lane] = w;
    }
    __syncthreads();
    int excl = sc - tot + (wave > 0 ? wsum[wave - 1] : 0);
    #pragma unroll
    for (int i = 0; i < SCAN_ITEMS; ++i) {
        int idx = base + i;
        if (idx < N) { offs[idx] = excl; cursor[idx] = excl; }
        excl += v[i];
    }
}

__global__ __launch_bounds__(256) void place_k(
    const int* __restrict__ src, const int* __restrict__ dst,
    const float* __restrict__ ea, int* __restrict__ cursor, int2* __restrict__ sorted)
{
    int e = blockIdx.x * 256 + threadIdx.x;
    int d = dst[e];
    int pos = atomicAdd(&cursor[d], 1);
    int2 pr; pr.x = src[e]; pr.y = __float_as_int(ea[e]);
    sorted[pos] = pr;
}

// ---- per-node aggregation, 4x unrolled edge loop (4 independent gather chains) ----
// PQ layout: [50048][256] bf16, cols 0:128 = P (x@W1a+b1), cols 128:256 = Q (x@W1b)
__global__ __launch_bounds__(256) void aggregate_k(
    const unsigned short* __restrict__ PQ,
    const int2* __restrict__ sorted, const int* __restrict__ offs, const int* __restrict__ cnt,
    const float* __restrict__ w1c, unsigned short* __restrict__ Hb)
{
    int wave = threadIdx.x >> 6, lane = threadIdx.x & 63;
    int n = blockIdx.x * 4 + wave;      // grid exactly covers 50000
    int i0 = lane * 2;
    float2 w = *(const float2*)(w1c + i0);
    ushort2 p2 = *(const ushort2*)(PQ + (long)n*256 + i0);
    float p0 = bf2f(p2.x), p1 = bf2f(p2.y);
    int s = offs[n], c = cnt[n];
    const unsigned short* Qb = PQ + 128 + i0;
    float a00 = 0.f, a01 = 0.f, a10 = 0.f, a11 = 0.f;
    float a20 = 0.f, a21 = 0.f, a30 = 0.f, a31 = 0.f;
    int j = 0;
    for (; j + 4 <= c; j += 4) {
        int2 e0 = sorted[s+j], e1 = sorted[s+j+1], e2 = sorted[s+j+2], e3 = sorted[s+j+3];
        ushort2 q0 = *(const ushort2*)(Qb + (long)e0.x*256);
        ushort2 q1 = *(const ushort2*)(Qb + (long)e1.x*256);
        ushort2 q2 = *(const ushort2*)(Qb + (long)e2.x*256);
        ushort2 q3 = *(const ushort2*)(Qb + (long)e3.x*256);
        float v0 = __int_as_float(e0.y), v1 = __int_as_float(e1.y);
        float v2 = __int_as_float(e2.y), v3 = __int_as_float(e3.y);
        a00 += fmaxf(p0 + bf2f(q0.x) + v0*w.x, 0.f);
        a01 += fmaxf(p1 + bf2f(q0.y) + v0*w.y, 0.f);
        a10 += fmaxf(p0 + bf2f(q1.x) + v1*w.x, 0.f);
        a11 += fmaxf(p1 + bf2f(q1.y) + v1*w.y, 0.f);
        a20 += fmaxf(p0 + bf2f(q2.x) + v2*w.x, 0.f);
        a21 += fmaxf(p1 + bf2f(q2.y) + v2*w.y, 0.f);
        a30 += fmaxf(p0 + bf2f(q3.x) + v3*w.x, 0.f);
        a31 += fmaxf(p1 + bf2f(q3.y) + v3*w.y, 0.f);
    }
    for (; j < c; ++j) {
        int2 e0 = sorted[s+j];
        ushort2 q0 = *(const ushort2*)(Qb + (long)e0.x*256);
        float v0 = __int_as_float(e0.y);
        a00 += fmaxf(p0 + bf2f(q0.x) + v0*w.x, 0.f);
        a01 += fmaxf(p1 + bf2f(q0.y) + v0*w.y, 0.f);
    }
    float a0 = (a00 + a10) + (a20 + a30);
    float a1 = (a01 + a11) + (a21 + a31);
    float inv = 1.0f / fmaxf((float)c, 1.0f);
    ushort2 o; o.x = f2bf(a0 * inv); o.y = f2bf(a1 * inv);
    *(ushort2*)(Hb + (long)n*128 + i0) = o;
}

// ---- MFMA GEMM, templated epilogue ----
// EPI: 0 = +bias(col<biasN)            (PQ gemm)
//      1 = +bias*[deg>0]               (W2 gemm)
//      2 = relu(+bias)                 (U1 gemm)
//      3 = relu(LN(+bias)*g+b)         (U2 gemm, fused layernorm)
#define EPI_BIAS 0
#define EPI_MASK 1
#define EPI_RELU 2
#define EPI_LN   3

template<int NT, int EPI>
__global__ __launch_bounds__(256) void gemm_k(
    const unsigned short* __restrict__ A, int lda,
    const unsigned short* __restrict__ Bt,   // [NT*16][K] bf16 (transposed)
    const float* __restrict__ bias, int biasN,
    const int* __restrict__ cnt,
    const float* __restrict__ lng, const float* __restrict__ lnb,
    unsigned short* __restrict__ C, int ldc, int M, int K)
{
    __shared__ unsigned short As[64][72];     // +8 pad
    __shared__ unsigned short Bs[NT*16][72];
    int tid = threadIdx.x;
    int wave = tid >> 6, lane = tid & 63;
    int row0 = blockIdx.x * 64;
    floatx4 zero = {0.f, 0.f, 0.f, 0.f};
    floatx4 acc[NT];
    #pragma unroll
    for (int t = 0; t < NT; ++t) acc[t] = zero;

    for (int k0 = 0; k0 < K; k0 += 64) {
        #pragma unroll
        for (int it = 0; it < 4; ++it) {      // A tile 64x64 (rows padded to 50048)
            int idx = it*1024 + tid*4;
            int r = idx >> 6, c = idx & 63;
            ushort4 v = *(const ushort4*)(A + (long)(row0 + r)*lda + k0 + c);
            *(ushort4*)(&As[r][c]) = v;
        }
        #pragma unroll
        for (int it = 0; it < NT; ++it) {     // B tile (NT*16)x64
            int idx = it*1024 + tid*4;
            int r = idx >> 6, c = idx & 63;
            ushort4 v = *(const ushort4*)(Bt + (long)r*K + k0 + c);
            *(ushort4*)(&Bs[r][c]) = v;
        }
        __syncthreads();
        #pragma unroll
        for (int kk = 0; kk < 64; kk += 32) {
            short8 af = *(const short8*)(&As[wave*16 + (lane & 15)][kk + (lane >> 4)*8]);
            #pragma unroll
            for (int t = 0; t < NT; ++t) {
                short8 bf = *(const short8*)(&Bs[t*16 + (lane & 15)][kk + (lane >> 4)*8]);
                acc[t] = __builtin_amdgcn_mfma_f32_16x16x32_bf16(af, bf, acc[t], 0, 0, 0);
            }
        }
        __syncthreads();
    }
    // C/D layout: col=lane&15, row=(lane>>4)*4+reg [m89/m91-verified]
    int col_lane = lane & 15;
    int rbase = row0 + wave*16 + (lane >> 4)*4;

    if (EPI == EPI_LN) {
        float rowsum[4] = {0.f,0.f,0.f,0.f}, rowsq[4] = {0.f,0.f,0.f,0.f};
        #pragma unroll
        for (int t = 0; t < NT; ++t) {
            float bv = bias[t*16 + col_lane];
            #pragma unroll
            for (int r = 0; r < 4; ++r) {
                acc[t][r] += bv;
                rowsum[r] += acc[t][r];
                rowsq[r]  += acc[t][r]*acc[t][r];
            }
        }
        #pragma unroll
        for (int o = 1; o < 16; o <<= 1) {
            #pragma unroll
            for (int r = 0; r < 4; ++r) {
                rowsum[r] += __shfl_xor(rowsum[r], o);
                rowsq[r]  += __shfl_xor(rowsq[r], o);
            }
        }
        float mu[4], rs[4];
        #pragma unroll
        for (int r = 0; r < 4; ++r) {
            mu[r] = rowsum[r] * (1.f/128.f);
            float var = rowsq[r] * (1.f/128.f) - mu[r]*mu[r];
            rs[r] = rsqrtf(var + 1e-5f);
        }
        #pragma unroll
        for (int t = 0; t < NT; ++t) {
            int col = t*16 + col_lane;
            float gv = lng[col], b2 = lnb[col];
            #pragma unroll
            for (int r = 0; r < 4; ++r) {
                int grow = rbase + r;
                if (grow < M) {
                    float y = fmaxf((acc[t][r] - mu[r]) * rs[r] * gv + b2, 0.f);
                    C[(long)grow*ldc + col] = f2bf(y);
                }
            }
        }
    } else {
        #pragma unroll
        for (int t = 0; t < NT; ++t) {
            int col = t*16 + col_lane;
            float bv = (col < biasN) ? bias[col] : 0.f;
            #pragma unroll
            for (int r = 0; r < 4; ++r) {
                int grow = rbase + r;
                if (grow < M) {
                    float v = acc[t][r];
                    float bb = bv;
                    if (EPI == EPI_MASK) bb = (cnt[grow] > 0) ? bv : 0.f;
                    v += bb;
                    if (EPI == EPI_RELU) v = fmaxf(v, 0.f);
                    C[(long)grow*ldc + col] = f2bf(v);
                }
            }
        }
    }
}

// ---- column sum over nodes (for the mean) ----
__global__ __launch_bounds__(256) void colsum_k(const unsigned short* __restrict__ u_in,
                                                float* __restrict__ sum, int N)
{
    __shared__ float buf[256];
    int c = threadIdx.x & 127, half = threadIdx.x >> 7;
    float a = 0.f;
    for (int n = blockIdx.x*2 + half; n < N; n += gridDim.x*2)
        a += bf2f(u_in[(long)n*256 + c]);
    buf[threadIdx.x] = a;
    __syncthreads();
    if (threadIdx.x < 128) atomicAdd(&sum[c], buf[threadIdx.x] + buf[threadIdx.x + 128]);
}

// ---- final tiny MLP on the mean (fp32) ----
__global__ __launch_bounds__(128) void final_k(
    const float* __restrict__ sum, const float* __restrict__ W1, const float* __restrict__ b1,
    const float* __restrict__ W2, const float* __restrict__ b2, float* __restrict__ out)
{
    __shared__ float gbuf[128], hbuf[128];
    int t = threadIdx.x;
    gbuf[t] = sum[t] * (1.f / 50000.f);
    __syncthreads();
    float a = b1[t];
    for (int k = 0; k < 128; ++k) a += gbuf[k] * W1[k*128 + t];
    hbuf[t] = fmaxf(a, 0.f);
    __syncthreads();
    float o = b2[t];
    for (int k = 0; k < 128; ++k) o += hbuf[k] * W2[k*128 + t];
    out[t] = o;
}

extern "C" void kernel_launch(void* const* d_in, const int* in_sizes, int n_in,
                              void* d_out, int out_size, void* d_ws, size_t ws_size,
                              hipStream_t stream)
{
    const float* node_feat = (const float*)d_in[0];
    const float* edge_attr = (const float*)d_in[1];
    const float* enc_W  = (const float*)d_in[2];
    const float* enc_b  = (const float*)d_in[3];
    const float* mlp_W1 = (const float*)d_in[4];
    const float* mlp_b1 = (const float*)d_in[5];
    const float* mlp_W2 = (const float*)d_in[6];
    const float* mlp_b2 = (const float*)d_in[7];
    const float* upd_W1 = (const float*)d_in[8];
    const float* upd_b1 = (const float*)d_in[9];
    const float* upd_W2 = (const float*)d_in[10];
    const float* upd_b2 = (const float*)d_in[11];
    const float* ln_g   = (const float*)d_in[12];
    const float* ln_b   = (const float*)d_in[13];
    const float* out_W1 = (const float*)d_in[14];
    const float* out_b1 = (const float*)d_in[15];
    const float* out_W2 = (const float*)d_in[16];
    const float* out_b2 = (const float*)d_in[17];
    const int* edge_index = (const int*)d_in[18];
    const int* e_src = edge_index;
    const int* e_dst = edge_index + NEDGES;

    // workspace layout (padded node rows = 50048)
    char* ws = (char*)d_ws;
    unsigned short* u_in = (unsigned short*)(ws + 0);          // [50048][256] bf16: [x | aggr]
    unsigned short* PQ   = (unsigned short*)(ws + 25624576);   // [50048][256] bf16: [P | Q]; reused as u_hid [50048][128]
    unsigned short* Hb   = (unsigned short*)(ws + 51249152);   // [50048][128] bf16
    int2* sorted         = (int2*)(ws + 64061440);             // [800000] {src, ea}
    int* cnt             = (int*)(ws + 70461440);              // [50048]
    int* offs            = (int*)(ws + 70661632);              // [50048]
    int* cursor          = (int*)(ws + 70861824);              // [50048]
    unsigned short* wt   = (unsigned short*)(ws + 71062016);   // [3*WPL] bf16 weights
    float* sumv          = (float*)(ws + 71651840);            // [128]

    hipMemsetAsync(cnt, 0, 50048*4, stream);
    hipMemsetAsync(sumv, 0, 512, stream);
    cvt_weights<<<1152, 256, 0, stream>>>(mlp_W1, mlp_W2, upd_W1, upd_W2, wt);
    encoder_k<<<25000, 256, 0, stream>>>(node_feat, enc_W, enc_b, u_in);
    hist_k<<<3125, 256, 0, stream>>>(e_dst, cnt);
    scan_k<<<1, 1024, 0, stream>>>(cnt, offs, cursor, NNODES);
    place_k<<<3125, 256, 0, stream>>>(e_src, e_dst, edge_attr, cursor, sorted);

    for (int l = 0; l < 3; ++l) {
        const unsigned short* wPQ = wt + l*WPL;            // [256][128]: W1a^T | W1b^T
        const unsigned short* w2t = wt + l*WPL + 32768;    // [128][128]
        const unsigned short* u1t = wt + l*WPL + 49152;    // [128][256]
        const unsigned short* u2t = wt + l*WPL + 81920;    // [128][128]
        // PQ = [x@W1a + b1 | x@W1b]
        gemm_k<16,EPI_BIAS><<<782, 256, 0, stream>>>(u_in, 256, wPQ, mlp_b1 + l*128, 128,
                                                     nullptr, nullptr, nullptr, PQ, 256, NNODES, 128);
        // Hb = inv_deg * segsum(relu(P[dst]+Q[src]+ea*w1c))
        aggregate_k<<<12500, 256, 0, stream>>>(PQ, sorted, offs, cnt,
                                               mlp_W1 + (l*257 + 256)*128, Hb);
        // aggr = Hb@W2 + b2*[deg>0]  -> u_in[:,128:256]
        gemm_k<8,EPI_MASK><<<782, 256, 0, stream>>>(Hb, 128, w2t, mlp_b2 + l*128, 128,
                                                    cnt, nullptr, nullptr, u_in + 128, 256, NNODES, 128);
        // u_hid = relu([x|aggr]@U1 + ub1)   (K=256) -> PQ (reused)
        gemm_k<8,EPI_RELU><<<782, 256, 0, stream>>>(u_in, 256, u1t, upd_b1 + l*128, 128,
                                                    nullptr, nullptr, nullptr, PQ, 128, NNODES, 256);
        // x = relu(LN(u_hid@U2 + ub2)*g+b) -> u_in[:,0:128]  (fused LN epilogue)
        gemm_k<8,EPI_LN><<<782, 256, 0, stream>>>(PQ, 128, u2t, upd_b2 + l*128, 128,
                                                  nullptr, ln_g + l*128, ln_b + l*128, u_in, 256, NNODES, 128);
    }
    colsum_k<<<256, 256, 0, stream>>>(u_in, sumv, NNODES);
    final_k<<<1, 128, 0, stream>>>(sumv, out_W1, out_b1, out_W2, out_b2, (float*)d_out);
}

// Round 4
// 657.618 us; speedup vs baseline: 1.3102x; 1.1170x over previous
//
#include <hip/hip_runtime.h>
#include <stdint.h>

#define HID 128
#define NNODES 50000
#define NEDGES 800000
#define WPL 98304  // bf16 weight elems per layer in wt scratch

typedef __attribute__((ext_vector_type(8))) short short8;
typedef __attribute__((ext_vector_type(4))) float floatx4;

__device__ __forceinline__ float bf2f(unsigned short h) {
    union { unsigned int u; float f; } v; v.u = ((unsigned int)h) << 16; return v.f;
}
__device__ __forceinline__ unsigned short f2bf(float f) {
    union { float f; unsigned int u; } v; v.f = f;
    unsigned int u = v.u;
    return (unsigned short)((u + 0x7fffu + ((u >> 16) & 1u)) >> 16);
}

// ---- convert all layer weights to bf16, transposed to [n][k] for MFMA B-frags ----
// layout per layer l: [W1a^T 128x128 | W1b^T 128x128 | W2^T 128x128 | U1^T 128x256 | U2^T 128x128]
__global__ __launch_bounds__(256) void cvt_weights(
    const float* __restrict__ mW1, const float* __restrict__ mW2,
    const float* __restrict__ uW1, const float* __restrict__ uW2,
    unsigned short* __restrict__ wt)
{
    int id = blockIdx.x * 256 + threadIdx.x;
    int l = id / WPL;
    int r = id - l * WPL;
    float v;
    if (r < 16384)      { int n = r >> 7, k = r & 127;                v = mW1[(l*257 + k)*128 + n]; }
    else if (r < 32768) { int q = r - 16384; int n = q >> 7, k = q & 127; v = mW1[(l*257 + 128 + k)*128 + n]; }
    else if (r < 49152) { int q = r - 32768; int n = q >> 7, k = q & 127; v = mW2[(l*128 + k)*128 + n]; }
    else if (r < 81920) { int q = r - 49152; int n = q >> 8, k = q & 255; v = uW1[(l*256 + k)*128 + n]; }
    else                { int q = r - 81920; int n = q >> 7, k = q & 127; v = uW2[(l*128 + k)*128 + n]; }
    wt[id] = f2bf(v);
}

// ---- encoder: x0 = node_feat @ enc_W + enc_b, write bf16 into u_in[:,0:128] ----
__global__ __launch_bounds__(256) void encoder_k(
    const float* __restrict__ nf, const float* __restrict__ W,
    const float* __restrict__ b, unsigned short* __restrict__ u_in)
{
    int id = blockIdx.x * 256 + threadIdx.x;   // exact: 50000*128 threads
    int n = id >> 7, c = id & 127;
    float acc = b[c];
    #pragma unroll
    for (int k = 0; k < 5; ++k) acc += nf[n*5 + k] * W[k*128 + c];
    u_in[n*256 + c] = f2bf(acc);
}

// ---- CSR build: histogram, 3-phase multi-block scan, placement ----
__global__ __launch_bounds__(256) void hist_k(const int* __restrict__ dst, int* __restrict__ cnt) {
    int e = blockIdx.x * 256 + threadIdx.x;
    atomicAdd(&cnt[dst[e]], 1);
}

// phase 1: 49 blocks x 256 threads, int4 per thread (50176 = 49*1024 padded, cnt zeroed)
__global__ __launch_bounds__(256) void scan1_k(const int* __restrict__ cnt,
                                               int* __restrict__ offs, int* __restrict__ btot)
{
    __shared__ int wsum[4];
    int tid = threadIdx.x, lane = tid & 63, wave = tid >> 6;
    int gid = blockIdx.x * 256 + tid;
    int4 v = ((const int4*)cnt)[gid];
    int tot = v.x + v.y + v.z + v.w;
    int sc = tot;
    #pragma unroll
    for (int o = 1; o < 64; o <<= 1) {
        int t = __shfl_up(sc, o);
        if (lane >= o) sc += t;
    }
    if (lane == 63) wsum[wave] = sc;
    __syncthreads();
    int woff = 0;
    #pragma unroll
    for (int i = 0; i < 3; ++i) if (i < wave) woff += wsum[i];
    int excl = woff + sc - tot;
    int4 o;
    o.x = excl; o.y = excl + v.x; o.z = o.y + v.y; o.w = o.z + v.z;
    ((int4*)offs)[gid] = o;
    if (tid == 255) btot[blockIdx.x] = woff + sc;   // block total
}

// phase 2: one wave scans 49 block totals -> exclusive
__global__ __launch_bounds__(64) void scan2_k(int* __restrict__ btot)
{
    int tid = threadIdx.x;
    int v = (tid < 49) ? btot[tid] : 0;
    int sc = v;
    #pragma unroll
    for (int o = 1; o < 64; o <<= 1) {
        int t = __shfl_up(sc, o);
        if (tid >= o) sc += t;
    }
    if (tid < 49) btot[tid] = sc - v;
}

// phase 3: add block prefix, fan out to offs + cursor
__global__ __launch_bounds__(256) void scan3_k(const int* __restrict__ btot,
                                               int* __restrict__ offs, int* __restrict__ cursor)
{
    int gid = blockIdx.x * 256 + threadIdx.x;
    int p = btot[blockIdx.x];
    int4 o = ((int4*)offs)[gid];
    o.x += p; o.y += p; o.z += p; o.w += p;
    ((int4*)offs)[gid] = o;
    ((int4*)cursor)[gid] = o;
}

__global__ __launch_bounds__(256) void place_k(
    const int* __restrict__ src, const int* __restrict__ dst,
    const float* __restrict__ ea, int* __restrict__ cursor, int2* __restrict__ sorted)
{
    int e = blockIdx.x * 256 + threadIdx.x;
    int d = dst[e];
    int pos = atomicAdd(&cursor[d], 1);
    int2 pr; pr.x = src[e]; pr.y = __float_as_int(ea[e]);
    sorted[pos] = pr;
}

// ---- per-node aggregation, 4x unrolled edge loop (4 independent gather chains) ----
// PQ layout: [50048][256] bf16, cols 0:128 = P (x@W1a+b1), cols 128:256 = Q (x@W1b)
__global__ __launch_bounds__(256) void aggregate_k(
    const unsigned short* __restrict__ PQ,
    const int2* __restrict__ sorted, const int* __restrict__ offs, const int* __restrict__ cnt,
    const float* __restrict__ w1c, unsigned short* __restrict__ Hb)
{
    int wave = threadIdx.x >> 6, lane = threadIdx.x & 63;
    int n = blockIdx.x * 4 + wave;      // grid exactly covers 50000
    int i0 = lane * 2;
    float2 w = *(const float2*)(w1c + i0);
    ushort2 p2 = *(const ushort2*)(PQ + (long)n*256 + i0);
    float p0 = bf2f(p2.x), p1 = bf2f(p2.y);
    int s = offs[n], c = cnt[n];
    const unsigned short* Qb = PQ + 128 + i0;
    float a00 = 0.f, a01 = 0.f, a10 = 0.f, a11 = 0.f;
    float a20 = 0.f, a21 = 0.f, a30 = 0.f, a31 = 0.f;
    int j = 0;
    for (; j + 4 <= c; j += 4) {
        int2 e0 = sorted[s+j], e1 = sorted[s+j+1], e2 = sorted[s+j+2], e3 = sorted[s+j+3];
        ushort2 q0 = *(const ushort2*)(Qb + (long)e0.x*256);
        ushort2 q1 = *(const ushort2*)(Qb + (long)e1.x*256);
        ushort2 q2 = *(const ushort2*)(Qb + (long)e2.x*256);
        ushort2 q3 = *(const ushort2*)(Qb + (long)e3.x*256);
        float v0 = __int_as_float(e0.y), v1 = __int_as_float(e1.y);
        float v2 = __int_as_float(e2.y), v3 = __int_as_float(e3.y);
        a00 += fmaxf(p0 + bf2f(q0.x) + v0*w.x, 0.f);
        a01 += fmaxf(p1 + bf2f(q0.y) + v0*w.y, 0.f);
        a10 += fmaxf(p0 + bf2f(q1.x) + v1*w.x, 0.f);
        a11 += fmaxf(p1 + bf2f(q1.y) + v1*w.y, 0.f);
        a20 += fmaxf(p0 + bf2f(q2.x) + v2*w.x, 0.f);
        a21 += fmaxf(p1 + bf2f(q2.y) + v2*w.y, 0.f);
        a30 += fmaxf(p0 + bf2f(q3.x) + v3*w.x, 0.f);
        a31 += fmaxf(p1 + bf2f(q3.y) + v3*w.y, 0.f);
    }
    for (; j < c; ++j) {
        int2 e0 = sorted[s+j];
        ushort2 q0 = *(const ushort2*)(Qb + (long)e0.x*256);
        float v0 = __int_as_float(e0.y);
        a00 += fmaxf(p0 + bf2f(q0.x) + v0*w.x, 0.f);
        a01 += fmaxf(p1 + bf2f(q0.y) + v0*w.y, 0.f);
    }
    float a0 = (a00 + a10) + (a20 + a30);
    float a1 = (a01 + a11) + (a21 + a31);
    float inv = 1.0f / fmaxf((float)c, 1.0f);
    ushort2 o; o.x = f2bf(a0 * inv); o.y = f2bf(a1 * inv);
    *(ushort2*)(Hb + (long)n*128 + i0) = o;
}

// ---- MFMA GEMM, templated epilogue ----
#define EPI_BIAS 0
#define EPI_MASK 1
#define EPI_RELU 2
#define EPI_LN   3

template<int NT, int EPI>
__global__ __launch_bounds__(256) void gemm_k(
    const unsigned short* __restrict__ A, int lda,
    const unsigned short* __restrict__ Bt,   // [NT*16][K] bf16 (transposed)
    const float* __restrict__ bias, int biasN,
    const int* __restrict__ cnt,
    const float* __restrict__ lng, const float* __restrict__ lnb,
    unsigned short* __restrict__ C, int ldc, int M, int K)
{
    __shared__ unsigned short As[64][72];     // +8 pad
    __shared__ unsigned short Bs[NT*16][72];
    int tid = threadIdx.x;
    int wave = tid >> 6, lane = tid & 63;
    int row0 = blockIdx.x * 64;
    floatx4 zero = {0.f, 0.f, 0.f, 0.f};
    floatx4 acc[NT];
    #pragma unroll
    for (int t = 0; t < NT; ++t) acc[t] = zero;

    for (int k0 = 0; k0 < K; k0 += 64) {
        #pragma unroll
        for (int it = 0; it < 4; ++it) {      // A tile 64x64 (rows padded to 50048)
            int idx = it*1024 + tid*4;
            int r = idx >> 6, c = idx & 63;
            ushort4 v = *(const ushort4*)(A + (long)(row0 + r)*lda + k0 + c);
            *(ushort4*)(&As[r][c]) = v;
        }
        #pragma unroll
        for (int it = 0; it < NT; ++it) {     // B tile (NT*16)x64
            int idx = it*1024 + tid*4;
            int r = idx >> 6, c = idx & 63;
            ushort4 v = *(const ushort4*)(Bt + (long)r*K + k0 + c);
            *(ushort4*)(&Bs[r][c]) = v;
        }
        __syncthreads();
        #pragma unroll
        for (int kk = 0; kk < 64; kk += 32) {
            short8 af = *(const short8*)(&As[wave*16 + (lane & 15)][kk + (lane >> 4)*8]);
            #pragma unroll
            for (int t = 0; t < NT; ++t) {
                short8 bf = *(const short8*)(&Bs[t*16 + (lane & 15)][kk + (lane >> 4)*8]);
                acc[t] = __builtin_amdgcn_mfma_f32_16x16x32_bf16(af, bf, acc[t], 0, 0, 0);
            }
        }
        __syncthreads();
    }
    // C/D layout: col=lane&15, row=(lane>>4)*4+reg [m89/m91-verified]
    int col_lane = lane & 15;
    int rbase = row0 + wave*16 + (lane >> 4)*4;

    if (EPI == EPI_LN) {
        float rowsum[4] = {0.f,0.f,0.f,0.f}, rowsq[4] = {0.f,0.f,0.f,0.f};
        #pragma unroll
        for (int t = 0; t < NT; ++t) {
            float bv = bias[t*16 + col_lane];
            #pragma unroll
            for (int r = 0; r < 4; ++r) {
                acc[t][r] += bv;
                rowsum[r] += acc[t][r];
                rowsq[r]  += acc[t][r]*acc[t][r];
            }
        }
        #pragma unroll
        for (int o = 1; o < 16; o <<= 1) {
            #pragma unroll
            for (int r = 0; r < 4; ++r) {
                rowsum[r] += __shfl_xor(rowsum[r], o);
                rowsq[r]  += __shfl_xor(rowsq[r], o);
            }
        }
        float mu[4], rs[4];
        #pragma unroll
        for (int r = 0; r < 4; ++r) {
            mu[r] = rowsum[r] * (1.f/128.f);
            float var = rowsq[r] * (1.f/128.f) - mu[r]*mu[r];
            rs[r] = rsqrtf(var + 1e-5f);
        }
        #pragma unroll
        for (int t = 0; t < NT; ++t) {
            int col = t*16 + col_lane;
            float gv = lng[col], b2 = lnb[col];
            #pragma unroll
            for (int r = 0; r < 4; ++r) {
                int grow = rbase + r;
                if (grow < M) {
                    float y = fmaxf((acc[t][r] - mu[r]) * rs[r] * gv + b2, 0.f);
                    C[(long)grow*ldc + col] = f2bf(y);
                }
            }
        }
    } else {
        #pragma unroll
        for (int t = 0; t < NT; ++t) {
            int col = t*16 + col_lane;
            float bv = (col < biasN) ? bias[col] : 0.f;
            #pragma unroll
            for (int r = 0; r < 4; ++r) {
                int grow = rbase + r;
                if (grow < M) {
                    float v = acc[t][r];
                    float bb = bv;
                    if (EPI == EPI_MASK) bb = (cnt[grow] > 0) ? bv : 0.f;
                    v += bb;
                    if (EPI == EPI_RELU) v = fmaxf(v, 0.f);
                    C[(long)grow*ldc + col] = f2bf(v);
                }
            }
        }
    }
}

// ---- column sum over nodes (for the mean) ----
__global__ __launch_bounds__(256) void colsum_k(const unsigned short* __restrict__ u_in,
                                                float* __restrict__ sum, int N)
{
    __shared__ float buf[256];
    int c = threadIdx.x & 127, half = threadIdx.x >> 7;
    float a = 0.f;
    for (int n = blockIdx.x*2 + half; n < N; n += gridDim.x*2)
        a += bf2f(u_in[(long)n*256 + c]);
    buf[threadIdx.x] = a;
    __syncthreads();
    if (threadIdx.x < 128) atomicAdd(&sum[c], buf[threadIdx.x] + buf[threadIdx.x + 128]);
}

// ---- final tiny MLP on the mean (fp32) ----
__global__ __launch_bounds__(128) void final_k(
    const float* __restrict__ sum, const float* __restrict__ W1, const float* __restrict__ b1,
    const float* __restrict__ W2, const float* __restrict__ b2, float* __restrict__ out)
{
    __shared__ float gbuf[128], hbuf[128];
    int t = threadIdx.x;
    gbuf[t] = sum[t] * (1.f / 50000.f);
    __syncthreads();
    float a = b1[t];
    for (int k = 0; k < 128; ++k) a += gbuf[k] * W1[k*128 + t];
    hbuf[t] = fmaxf(a, 0.f);
    __syncthreads();
    float o = b2[t];
    for (int k = 0; k < 128; ++k) o += hbuf[k] * W2[k*128 + t];
    out[t] = o;
}

extern "C" void kernel_launch(void* const* d_in, const int* in_sizes, int n_in,
                              void* d_out, int out_size, void* d_ws, size_t ws_size,
                              hipStream_t stream)
{
    const float* node_feat = (const float*)d_in[0];
    const float* edge_attr = (const float*)d_in[1];
    const float* enc_W  = (const float*)d_in[2];
    const float* enc_b  = (const float*)d_in[3];
    const float* mlp_W1 = (const float*)d_in[4];
    const float* mlp_b1 = (const float*)d_in[5];
    const float* mlp_W2 = (const float*)d_in[6];
    const float* mlp_b2 = (const float*)d_in[7];
    const float* upd_W1 = (const float*)d_in[8];
    const float* upd_b1 = (const float*)d_in[9];
    const float* upd_W2 = (const float*)d_in[10];
    const float* upd_b2 = (const float*)d_in[11];
    const float* ln_g   = (const float*)d_in[12];
    const float* ln_b   = (const float*)d_in[13];
    const float* out_W1 = (const float*)d_in[14];
    const float* out_b1 = (const float*)d_in[15];
    const float* out_W2 = (const float*)d_in[16];
    const float* out_b2 = (const float*)d_in[17];
    const int* edge_index = (const int*)d_in[18];
    const int* e_src = edge_index;
    const int* e_dst = edge_index + NEDGES;

    // workspace layout (padded node rows = 50048; scan arrays padded to 50176 = 49*1024)
    char* ws = (char*)d_ws;
    unsigned short* u_in = (unsigned short*)(ws + 0);          // [50048][256] bf16: [x | aggr]
    unsigned short* PQ   = (unsigned short*)(ws + 25624576);   // [50048][256] bf16: [P | Q]; reused as u_hid
    unsigned short* Hb   = (unsigned short*)(ws + 51249152);   // [50048][128] bf16
    int2* sorted         = (int2*)(ws + 64061440);             // [800000] {src, ea}
    int* cnt             = (int*)(ws + 70461440);              // [50176]
    int* offs            = (int*)(ws + 70662144);              // [50176]
    int* cursor          = (int*)(ws + 70862848);              // [50176]
    int* btot            = (int*)(ws + 71063552);              // [64]
    unsigned short* wt   = (unsigned short*)(ws + 71064064);   // [3*WPL] bf16 weights
    float* sumv          = (float*)(ws + 71653888);            // [128]

    hipMemsetAsync(cnt, 0, 50176*4, stream);
    hipMemsetAsync(sumv, 0, 512, stream);
    cvt_weights<<<1152, 256, 0, stream>>>(mlp_W1, mlp_W2, upd_W1, upd_W2, wt);
    encoder_k<<<25000, 256, 0, stream>>>(node_feat, enc_W, enc_b, u_in);
    hist_k<<<3125, 256, 0, stream>>>(e_dst, cnt);
    scan1_k<<<49, 256, 0, stream>>>(cnt, offs, btot);
    scan2_k<<<1, 64, 0, stream>>>(btot);
    scan3_k<<<49, 256, 0, stream>>>(btot, offs, cursor);
    place_k<<<3125, 256, 0, stream>>>(e_src, e_dst, edge_attr, cursor, sorted);

    for (int l = 0; l < 3; ++l) {
        const unsigned short* wPQ = wt + l*WPL;            // [256][128]: W1a^T | W1b^T
        const unsigned short* w2t = wt + l*WPL + 32768;    // [128][128]
        const unsigned short* u1t = wt + l*WPL + 49152;    // [128][256]
        const unsigned short* u2t = wt + l*WPL + 81920;    // [128][128]
        // PQ = [x@W1a + b1 | x@W1b]
        gemm_k<16,EPI_BIAS><<<782, 256, 0, stream>>>(u_in, 256, wPQ, mlp_b1 + l*128, 128,
                                                     nullptr, nullptr, nullptr, PQ, 256, NNODES, 128);
        // Hb = inv_deg * segsum(relu(P[dst]+Q[src]+ea*w1c))
        aggregate_k<<<12500, 256, 0, stream>>>(PQ, sorted, offs, cnt,
                                               mlp_W1 + (l*257 + 256)*128, Hb);
        // aggr = Hb@W2 + b2*[deg>0]  -> u_in[:,128:256]
        gemm_k<8,EPI_MASK><<<782, 256, 0, stream>>>(Hb, 128, w2t, mlp_b2 + l*128, 128,
                                                    cnt, nullptr, nullptr, u_in + 128, 256, NNODES, 128);
        // u_hid = relu([x|aggr]@U1 + ub1)   (K=256) -> PQ (reused)
        gemm_k<8,EPI_RELU><<<782, 256, 0, stream>>>(u_in, 256, u1t, upd_b1 + l*128, 128,
                                                    nullptr, nullptr, nullptr, PQ, 128, NNODES, 256);
        // x = relu(LN(u_hid@U2 + ub2)*g+b) -> u_in[:,0:128]  (fused LN epilogue)
        gemm_k<8,EPI_LN><<<782, 256, 0, stream>>>(PQ, 128, u2t, upd_b2 + l*128, 128,
                                                  nullptr, ln_g + l*128, ln_b + l*128, u_in, 256, NNODES, 128);
    }
    colsum_k<<<256, 256, 0, stream>>>(u_in, sumv, NNODES);
    final_k<<<1, 128, 0, stream>>>(sumv, out_W1, out_b1, out_W2, out_b2, (float*)d_out);
}

// Round 5
// 505.459 us; speedup vs baseline: 1.7046x; 1.3010x over previous
//
#include <hip/hip_runtime.h>
#include <stdint.h>

#define HID 128
#define NNODES 50000
#define NEDGES 800000
#define WPL 98304  // bf16 weight elems per layer in wt scratch

typedef __attribute__((ext_vector_type(8))) short short8;
typedef __attribute__((ext_vector_type(4))) float floatx4;

__device__ __forceinline__ float bf2f(unsigned short h) {
    union { unsigned int u; float f; } v; v.u = ((unsigned int)h) << 16; return v.f;
}
__device__ __forceinline__ unsigned short f2bf(float f) {
    union { float f; unsigned int u; } v; v.f = f;
    unsigned int u = v.u;
    return (unsigned short)((u + 0x7fffu + ((u >> 16) & 1u)) >> 16);
}

// ---- convert all layer weights to bf16, transposed to [n][k] for MFMA B-frags ----
// layout per layer l: [W1a^T 128x128 | W1b^T 128x128 | W2^T 128x128 | U1^T 128x256 | U2^T 128x128]
__global__ __launch_bounds__(256) void cvt_weights(
    const float* __restrict__ mW1, const float* __restrict__ mW2,
    const float* __restrict__ uW1, const float* __restrict__ uW2,
    unsigned short* __restrict__ wt)
{
    int id = blockIdx.x * 256 + threadIdx.x;
    int l = id / WPL;
    int r = id - l * WPL;
    float v;
    if (r < 16384)      { int n = r >> 7, k = r & 127;                v = mW1[(l*257 + k)*128 + n]; }
    else if (r < 32768) { int q = r - 16384; int n = q >> 7, k = q & 127; v = mW1[(l*257 + 128 + k)*128 + n]; }
    else if (r < 49152) { int q = r - 32768; int n = q >> 7, k = q & 127; v = mW2[(l*128 + k)*128 + n]; }
    else if (r < 81920) { int q = r - 49152; int n = q >> 8, k = q & 255; v = uW1[(l*256 + k)*128 + n]; }
    else                { int q = r - 81920; int n = q >> 7, k = q & 127; v = uW2[(l*128 + k)*128 + n]; }
    wt[id] = f2bf(v);
}

// ---- encoder: x0 = node_feat @ enc_W + enc_b, write bf16 into u_in[:,0:128] ----
__global__ __launch_bounds__(256) void encoder_k(
    const float* __restrict__ nf, const float* __restrict__ W,
    const float* __restrict__ b, unsigned short* __restrict__ u_in)
{
    int id = blockIdx.x * 256 + threadIdx.x;   // exact: 50000*128 threads
    int n = id >> 7, c = id & 127;
    float acc = b[c];
    #pragma unroll
    for (int k = 0; k < 5; ++k) acc += nf[n*5 + k] * W[k*128 + c];
    u_in[n*256 + c] = f2bf(acc);
}

// ---- CSR build: histogram, 3-phase multi-block scan, placement ----
__global__ __launch_bounds__(256) void hist_k(const int* __restrict__ dst, int* __restrict__ cnt) {
    int e = blockIdx.x * 256 + threadIdx.x;
    atomicAdd(&cnt[dst[e]], 1);
}

__global__ __launch_bounds__(256) void scan1_k(const int* __restrict__ cnt,
                                               int* __restrict__ offs, int* __restrict__ btot)
{
    __shared__ int wsum[4];
    int tid = threadIdx.x, lane = tid & 63, wave = tid >> 6;
    int gid = blockIdx.x * 256 + tid;
    int4 v = ((const int4*)cnt)[gid];
    int tot = v.x + v.y + v.z + v.w;
    int sc = tot;
    #pragma unroll
    for (int o = 1; o < 64; o <<= 1) {
        int t = __shfl_up(sc, o);
        if (lane >= o) sc += t;
    }
    if (lane == 63) wsum[wave] = sc;
    __syncthreads();
    int woff = 0;
    #pragma unroll
    for (int i = 0; i < 3; ++i) if (i < wave) woff += wsum[i];
    int excl = woff + sc - tot;
    int4 o;
    o.x = excl; o.y = excl + v.x; o.z = o.y + v.y; o.w = o.z + v.z;
    ((int4*)offs)[gid] = o;
    if (tid == 255) btot[blockIdx.x] = woff + sc;
}

__global__ __launch_bounds__(64) void scan2_k(int* __restrict__ btot)
{
    int tid = threadIdx.x;
    int v = (tid < 49) ? btot[tid] : 0;
    int sc = v;
    #pragma unroll
    for (int o = 1; o < 64; o <<= 1) {
        int t = __shfl_up(sc, o);
        if (tid >= o) sc += t;
    }
    if (tid < 49) btot[tid] = sc - v;
}

__global__ __launch_bounds__(256) void scan3_k(const int* __restrict__ btot,
                                               int* __restrict__ offs, int* __restrict__ cursor)
{
    int gid = blockIdx.x * 256 + threadIdx.x;
    int p = btot[blockIdx.x];
    int4 o = ((int4*)offs)[gid];
    o.x += p; o.y += p; o.z += p; o.w += p;
    ((int4*)offs)[gid] = o;
    ((int4*)cursor)[gid] = o;
}

__global__ __launch_bounds__(256) void place_k(
    const int* __restrict__ src, const int* __restrict__ dst,
    const float* __restrict__ ea, int* __restrict__ cursor, int2* __restrict__ sorted)
{
    int e = blockIdx.x * 256 + threadIdx.x;
    int d = dst[e];
    int pos = atomicAdd(&cursor[d], 1);
    int2 pr; pr.x = src[e]; pr.y = __float_as_int(ea[e]);
    sorted[pos] = pr;
}

// ---- per-node aggregation, 4x unrolled edge loop (4 independent gather chains) ----
// PQ layout: [50048][256] bf16, cols 0:128 = P (x@W1a+b1), cols 128:256 = Q (x@W1b)
__global__ __launch_bounds__(256) void aggregate_k(
    const unsigned short* __restrict__ PQ,
    const int2* __restrict__ sorted, const int* __restrict__ offs, const int* __restrict__ cnt,
    const float* __restrict__ w1c, unsigned short* __restrict__ Hb)
{
    int wave = threadIdx.x >> 6, lane = threadIdx.x & 63;
    int n = blockIdx.x * 4 + wave;      // grid exactly covers 50000
    int i0 = lane * 2;
    float2 w = *(const float2*)(w1c + i0);
    ushort2 p2 = *(const ushort2*)(PQ + (long)n*256 + i0);
    float p0 = bf2f(p2.x), p1 = bf2f(p2.y);
    int s = offs[n], c = cnt[n];
    const unsigned short* Qb = PQ + 128 + i0;
    float a00 = 0.f, a01 = 0.f, a10 = 0.f, a11 = 0.f;
    float a20 = 0.f, a21 = 0.f, a30 = 0.f, a31 = 0.f;
    int j = 0;
    for (; j + 4 <= c; j += 4) {
        int2 e0 = sorted[s+j], e1 = sorted[s+j+1], e2 = sorted[s+j+2], e3 = sorted[s+j+3];
        ushort2 q0 = *(const ushort2*)(Qb + (long)e0.x*256);
        ushort2 q1 = *(const ushort2*)(Qb + (long)e1.x*256);
        ushort2 q2 = *(const ushort2*)(Qb + (long)e2.x*256);
        ushort2 q3 = *(const ushort2*)(Qb + (long)e3.x*256);
        float v0 = __int_as_float(e0.y), v1 = __int_as_float(e1.y);
        float v2 = __int_as_float(e2.y), v3 = __int_as_float(e3.y);
        a00 += fmaxf(p0 + bf2f(q0.x) + v0*w.x, 0.f);
        a01 += fmaxf(p1 + bf2f(q0.y) + v0*w.y, 0.f);
        a10 += fmaxf(p0 + bf2f(q1.x) + v1*w.x, 0.f);
        a11 += fmaxf(p1 + bf2f(q1.y) + v1*w.y, 0.f);
        a20 += fmaxf(p0 + bf2f(q2.x) + v2*w.x, 0.f);
        a21 += fmaxf(p1 + bf2f(q2.y) + v2*w.y, 0.f);
        a30 += fmaxf(p0 + bf2f(q3.x) + v3*w.x, 0.f);
        a31 += fmaxf(p1 + bf2f(q3.y) + v3*w.y, 0.f);
    }
    for (; j < c; ++j) {
        int2 e0 = sorted[s+j];
        ushort2 q0 = *(const ushort2*)(Qb + (long)e0.x*256);
        float v0 = __int_as_float(e0.y);
        a00 += fmaxf(p0 + bf2f(q0.x) + v0*w.x, 0.f);
        a01 += fmaxf(p1 + bf2f(q0.y) + v0*w.y, 0.f);
    }
    float a0 = (a00 + a10) + (a20 + a30);
    float a1 = (a01 + a11) + (a21 + a31);
    float inv = 1.0f / fmaxf((float)c, 1.0f);
    ushort2 o; o.x = f2bf(a0 * inv); o.y = f2bf(a1 * inv);
    *(ushort2*)(Hb + (long)n*128 + i0) = o;
}

// ---- standalone MFMA GEMM (only used for the initial PQ0 = x0 @ [W1a|W1b] + b1) ----
__global__ __launch_bounds__(256) void gemm_pq_k(
    const unsigned short* __restrict__ A, int lda,
    const unsigned short* __restrict__ Bt,   // [256][128]
    const float* __restrict__ bias,          // first 128 cols only
    unsigned short* __restrict__ C, int ldc, int M, int K)
{
    __shared__ unsigned short As[64][72];
    __shared__ unsigned short Bs[256][72];
    int tid = threadIdx.x;
    int wave = tid >> 6, lane = tid & 63;
    int row0 = blockIdx.x * 64;
    floatx4 zero = {0.f, 0.f, 0.f, 0.f};
    floatx4 acc[16];
    #pragma unroll
    for (int t = 0; t < 16; ++t) acc[t] = zero;

    for (int k0 = 0; k0 < K; k0 += 64) {
        #pragma unroll
        for (int it = 0; it < 4; ++it) {
            int idx = it*1024 + tid*4;
            int r = idx >> 6, c = idx & 63;
            *(ushort4*)(&As[r][c]) = *(const ushort4*)(A + (long)(row0 + r)*lda + k0 + c);
        }
        #pragma unroll
        for (int it = 0; it < 16; ++it) {
            int idx = it*1024 + tid*4;
            int r = idx >> 6, c = idx & 63;
            *(ushort4*)(&Bs[r][c]) = *(const ushort4*)(Bt + (long)r*K + k0 + c);
        }
        __syncthreads();
        #pragma unroll
        for (int kk = 0; kk < 64; kk += 32) {
            short8 af = *(const short8*)(&As[wave*16 + (lane & 15)][kk + (lane >> 4)*8]);
            #pragma unroll
            for (int t = 0; t < 16; ++t) {
                short8 bf = *(const short8*)(&Bs[t*16 + (lane & 15)][kk + (lane >> 4)*8]);
                acc[t] = __builtin_amdgcn_mfma_f32_16x16x32_bf16(af, bf, acc[t], 0, 0, 0);
            }
        }
        __syncthreads();
    }
    int col_lane = lane & 15;
    int rbase = row0 + wave*16 + (lane >> 4)*4;
    #pragma unroll
    for (int t = 0; t < 16; ++t) {
        int col = t*16 + col_lane;
        float bv = (col < 128) ? bias[col] : 0.f;
        #pragma unroll
        for (int r = 0; r < 4; ++r) {
            int grow = rbase + r;
            if (grow < M) C[(long)grow*ldc + col] = f2bf(acc[t][r] + bv);
        }
    }
}

// ---- fused per-layer update: aggr=Hb@W2 -> u_hid=relu([x|aggr]@U1) -> x'=relu(LN(u_hid@U2))
//      -> (optional) PQ' = x'@W1ab[l+1] + b1'. Intermediates live in LDS only. ----
__global__ __launch_bounds__(256) void fused_update_k(
    const unsigned short* __restrict__ Hb,      // [50048][128]
    const unsigned short* __restrict__ w2t,     // [128][128]
    const unsigned short* __restrict__ u1t,     // [128][256]
    const unsigned short* __restrict__ u2t,     // [128][128]
    const unsigned short* __restrict__ w1abt,   // [256][128] next-layer, or null
    const float* __restrict__ mb2, const int* __restrict__ cnt,
    const float* __restrict__ ub1, const float* __restrict__ ub2,
    const float* __restrict__ lng, const float* __restrict__ lnb,
    const float* __restrict__ mb1n,             // next-layer b1, or null
    unsigned short* __restrict__ u_in,          // x at stride 256 (read cols 0:128, write x')
    unsigned short* __restrict__ PQ)            // [50048][256] out (if w1abt)
{
    __shared__ unsigned short As[64][72];
    __shared__ unsigned short Bs[128][72];
    __shared__ unsigned short buf[64][136];     // inter-stage A operand (aggr/u_hid/x')
    int tid = threadIdx.x;
    int wave = tid >> 6, lane = tid & 63;
    int col_lane = lane & 15, quad = lane >> 4;
    int row0 = blockIdx.x * 64;
    int lrow_base = wave*16 + quad*4;           // local row base in C-layout
    floatx4 zero = {0.f, 0.f, 0.f, 0.f};
    floatx4 acc[8];

#define STAGE_A(ptr, stride, k0) { _Pragma("unroll") \
    for (int it = 0; it < 4; ++it) { int idx = it*1024 + tid*4; int r = idx >> 6, c = idx & 63; \
        *(ushort4*)(&As[r][c]) = *(const ushort4*)((ptr) + (long)(row0 + r)*(stride) + (k0) + c); } }
#define STAGE_B(ptr, stride, k0) { _Pragma("unroll") \
    for (int it = 0; it < 8; ++it) { int idx = it*1024 + tid*4; int r = idx >> 6, c = idx & 63; \
        *(ushort4*)(&Bs[r][c]) = *(const ushort4*)((ptr) + (long)r*(stride) + (k0) + c); } }
#define MFMA_AS() { _Pragma("unroll") for (int kk = 0; kk < 64; kk += 32) { \
    short8 af = *(const short8*)(&As[wave*16 + col_lane][kk + quad*8]); \
    _Pragma("unroll") for (int t = 0; t < 8; ++t) { \
        short8 bf = *(const short8*)(&Bs[t*16 + col_lane][kk + quad*8]); \
        acc[t] = __builtin_amdgcn_mfma_f32_16x16x32_bf16(af, bf, acc[t], 0, 0, 0); } } }
#define MFMA_BUF(k0) { _Pragma("unroll") for (int kk = 0; kk < 64; kk += 32) { \
    short8 af = *(const short8*)(&buf[wave*16 + col_lane][(k0) + kk + quad*8]); \
    _Pragma("unroll") for (int t = 0; t < 8; ++t) { \
        short8 bf = *(const short8*)(&Bs[t*16 + col_lane][kk + quad*8]); \
        acc[t] = __builtin_amdgcn_mfma_f32_16x16x32_bf16(af, bf, acc[t], 0, 0, 0); } } }

    // ---------- step 1: aggr = Hb@W2 + mb2*[deg>0] -> buf ----------
    #pragma unroll
    for (int t = 0; t < 8; ++t) acc[t] = zero;
    for (int k0 = 0; k0 < 128; k0 += 64) {
        STAGE_A(Hb, 128, k0);
        STAGE_B(w2t, 128, k0);
        __syncthreads();
        MFMA_AS();
        __syncthreads();
    }
    float maskr[4];
    #pragma unroll
    for (int r = 0; r < 4; ++r) maskr[r] = (cnt[row0 + lrow_base + r] > 0) ? 1.f : 0.f;
    #pragma unroll
    for (int t = 0; t < 8; ++t) {
        int col = t*16 + col_lane;
        float bv = mb2[col];
        #pragma unroll
        for (int r = 0; r < 4; ++r)
            buf[lrow_base + r][col] = f2bf(acc[t][r] + bv * maskr[r]);
    }
    __syncthreads();

    // ---------- step 2: u_hid = relu(x@U1a + aggr@U1b + ub1) -> buf ----------
    #pragma unroll
    for (int t = 0; t < 8; ++t) acc[t] = zero;
    for (int k0 = 0; k0 < 128; k0 += 64) {       // x part (global), U1 k-cols 0..128
        STAGE_A(u_in, 256, k0);
        STAGE_B(u1t, 256, k0);
        __syncthreads();
        MFMA_AS();
        __syncthreads();
    }
    for (int k0 = 0; k0 < 128; k0 += 64) {       // aggr part (LDS), U1 k-cols 128..256
        STAGE_B(u1t, 256, 128 + k0);
        __syncthreads();
        MFMA_BUF(k0);
        __syncthreads();
    }
    #pragma unroll
    for (int t = 0; t < 8; ++t) {
        int col = t*16 + col_lane;
        float bv = ub1[col];
        #pragma unroll
        for (int r = 0; r < 4; ++r)
            buf[lrow_base + r][col] = f2bf(fmaxf(acc[t][r] + bv, 0.f));
    }
    __syncthreads();

    // ---------- step 3: y = u_hid@U2 + ub2 ; x' = relu(LN(y)*g+b) -> global + buf ----------
    #pragma unroll
    for (int t = 0; t < 8; ++t) acc[t] = zero;
    for (int k0 = 0; k0 < 128; k0 += 64) {
        STAGE_B(u2t, 128, k0);
        __syncthreads();
        MFMA_BUF(k0);
        __syncthreads();
    }
    {
        float rowsum[4] = {0.f,0.f,0.f,0.f}, rowsq[4] = {0.f,0.f,0.f,0.f};
        #pragma unroll
        for (int t = 0; t < 8; ++t) {
            float bv = ub2[t*16 + col_lane];
            #pragma unroll
            for (int r = 0; r < 4; ++r) {
                acc[t][r] += bv;
                rowsum[r] += acc[t][r];
                rowsq[r]  += acc[t][r]*acc[t][r];
            }
        }
        #pragma unroll
        for (int o = 1; o < 16; o <<= 1) {
            #pragma unroll
            for (int r = 0; r < 4; ++r) {
                rowsum[r] += __shfl_xor(rowsum[r], o);
                rowsq[r]  += __shfl_xor(rowsq[r], o);
            }
        }
        float mu[4], rs[4];
        #pragma unroll
        for (int r = 0; r < 4; ++r) {
            mu[r] = rowsum[r] * (1.f/128.f);
            float var = rowsq[r] * (1.f/128.f) - mu[r]*mu[r];
            rs[r] = rsqrtf(var + 1e-5f);
        }
        #pragma unroll
        for (int t = 0; t < 8; ++t) {
            int col = t*16 + col_lane;
            float gv = lng[col], bb = lnb[col];
            #pragma unroll
            for (int r = 0; r < 4; ++r) {
                unsigned short h = f2bf(fmaxf((acc[t][r] - mu[r]) * rs[r] * gv + bb, 0.f));
                int grow = row0 + lrow_base + r;
                if (grow < NNODES) u_in[(long)grow*256 + col] = h;
                buf[lrow_base + r][col] = h;
            }
        }
    }

    // ---------- step 4: PQ' = x'@W1ab' (+b1' on P half) ----------
    if (w1abt) {
        __syncthreads();
        #pragma unroll
        for (int half = 0; half < 2; ++half) {
            #pragma unroll
            for (int t = 0; t < 8; ++t) acc[t] = zero;
            for (int k0 = 0; k0 < 128; k0 += 64) {
                STAGE_B(w1abt + (long)half*128*128, 128, k0);
                __syncthreads();
                MFMA_BUF(k0);
                __syncthreads();
            }
            #pragma unroll
            for (int t = 0; t < 8; ++t) {
                int col = t*16 + col_lane;
                float bv = (half == 0) ? mb1n[col] : 0.f;
                #pragma unroll
                for (int r = 0; r < 4; ++r) {
                    int grow = row0 + lrow_base + r;
                    PQ[(long)grow*256 + half*128 + col] = f2bf(acc[t][r] + bv);
                }
            }
        }
    }
#undef STAGE_A
#undef STAGE_B
#undef MFMA_AS
#undef MFMA_BUF
}

// ---- column sum over nodes (for the mean) ----
__global__ __launch_bounds__(256) void colsum_k(const unsigned short* __restrict__ u_in,
                                                float* __restrict__ sum, int N)
{
    __shared__ float buf[256];
    int c = threadIdx.x & 127, half = threadIdx.x >> 7;
    float a = 0.f;
    for (int n = blockIdx.x*2 + half; n < N; n += gridDim.x*2)
        a += bf2f(u_in[(long)n*256 + c]);
    buf[threadIdx.x] = a;
    __syncthreads();
    if (threadIdx.x < 128) atomicAdd(&sum[c], buf[threadIdx.x] + buf[threadIdx.x + 128]);
}

// ---- final tiny MLP on the mean (fp32) ----
__global__ __launch_bounds__(128) void final_k(
    const float* __restrict__ sum, const float* __restrict__ W1, const float* __restrict__ b1,
    const float* __restrict__ W2, const float* __restrict__ b2, float* __restrict__ out)
{
    __shared__ float gbuf[128], hbuf[128];
    int t = threadIdx.x;
    gbuf[t] = sum[t] * (1.f / 50000.f);
    __syncthreads();
    float a = b1[t];
    for (int k = 0; k < 128; ++k) a += gbuf[k] * W1[k*128 + t];
    hbuf[t] = fmaxf(a, 0.f);
    __syncthreads();
    float o = b2[t];
    for (int k = 0; k < 128; ++k) o += hbuf[k] * W2[k*128 + t];
    out[t] = o;
}

extern "C" void kernel_launch(void* const* d_in, const int* in_sizes, int n_in,
                              void* d_out, int out_size, void* d_ws, size_t ws_size,
                              hipStream_t stream)
{
    const float* node_feat = (const float*)d_in[0];
    const float* edge_attr = (const float*)d_in[1];
    const float* enc_W  = (const float*)d_in[2];
    const float* enc_b  = (const float*)d_in[3];
    const float* mlp_W1 = (const float*)d_in[4];
    const float* mlp_b1 = (const float*)d_in[5];
    const float* mlp_W2 = (const float*)d_in[6];
    const float* mlp_b2 = (const float*)d_in[7];
    const float* upd_W1 = (const float*)d_in[8];
    const float* upd_b1 = (const float*)d_in[9];
    const float* upd_W2 = (const float*)d_in[10];
    const float* upd_b2 = (const float*)d_in[11];
    const float* ln_g   = (const float*)d_in[12];
    const float* ln_b   = (const float*)d_in[13];
    const float* out_W1 = (const float*)d_in[14];
    const float* out_b1 = (const float*)d_in[15];
    const float* out_W2 = (const float*)d_in[16];
    const float* out_b2 = (const float*)d_in[17];
    const int* edge_index = (const int*)d_in[18];
    const int* e_src = edge_index;
    const int* e_dst = edge_index + NEDGES;

    // workspace layout (padded node rows = 50048; scan arrays padded to 50176 = 49*1024)
    char* ws = (char*)d_ws;
    unsigned short* u_in = (unsigned short*)(ws + 0);          // [50048][256] bf16: [x | scratch]
    unsigned short* PQ   = (unsigned short*)(ws + 25624576);   // [50048][256] bf16: [P | Q]
    unsigned short* Hb   = (unsigned short*)(ws + 51249152);   // [50048][128] bf16
    int2* sorted         = (int2*)(ws + 64061440);             // [800000] {src, ea}
    int* cnt             = (int*)(ws + 70461440);              // [50176]
    int* offs            = (int*)(ws + 70662144);              // [50176]
    int* cursor          = (int*)(ws + 70862848);              // [50176]
    int* btot            = (int*)(ws + 71063552);              // [64]
    unsigned short* wt   = (unsigned short*)(ws + 71064064);   // [3*WPL] bf16 weights
    float* sumv          = (float*)(ws + 71653888);            // [128]

    hipMemsetAsync(cnt, 0, 50176*4, stream);
    hipMemsetAsync(sumv, 0, 512, stream);
    cvt_weights<<<1152, 256, 0, stream>>>(mlp_W1, mlp_W2, upd_W1, upd_W2, wt);
    encoder_k<<<25000, 256, 0, stream>>>(node_feat, enc_W, enc_b, u_in);
    hist_k<<<3125, 256, 0, stream>>>(e_dst, cnt);
    scan1_k<<<49, 256, 0, stream>>>(cnt, offs, btot);
    scan2_k<<<1, 64, 0, stream>>>(btot);
    scan3_k<<<49, 256, 0, stream>>>(btot, offs, cursor);
    place_k<<<3125, 256, 0, stream>>>(e_src, e_dst, edge_attr, cursor, sorted);

    // PQ0 = x0 @ [W1a|W1b] + b1 (layer 0 weights)
    gemm_pq_k<<<782, 256, 0, stream>>>(u_in, 256, wt, mlp_b1, PQ, 256, NNODES, 128);

    for (int l = 0; l < 3; ++l) {
        const unsigned short* w2t = wt + l*WPL + 32768;    // [128][128]
        const unsigned short* u1t = wt + l*WPL + 49152;    // [128][256]
        const unsigned short* u2t = wt + l*WPL + 81920;    // [128][128]
        // Hb = inv_deg * segsum(relu(P[dst]+Q[src]+ea*w1c))
        aggregate_k<<<12500, 256, 0, stream>>>(PQ, sorted, offs, cnt,
                                               mlp_W1 + (l*257 + 256)*128, Hb);
        // fused: aggr -> u_hid -> x' (LN) -> PQ for layer l+1
        fused_update_k<<<782, 256, 0, stream>>>(
            Hb, w2t, u1t, u2t,
            (l < 2) ? (wt + (l+1)*WPL) : nullptr,
            mlp_b2 + l*128, cnt,
            upd_b1 + l*128, upd_b2 + l*128,
            ln_g + l*128, ln_b + l*128,
            (l < 2) ? (mlp_b1 + (l+1)*128) : nullptr,
            u_in, PQ);
    }
    colsum_k<<<256, 256, 0, stream>>>(u_in, sumv, NNODES);
    final_k<<<1, 128, 0, stream>>>(sumv, out_W1, out_b1, out_W2, out_b2, (float*)d_out);
}